// Round 1
// baseline (275.554 us; speedup 1.0000x reference)
//
#include <hip/hip_runtime.h>
#include <hip/hip_bf16.h>
#include <stdint.h>

#define NBATCH 4
#define NV 2048
#define NC 8192
#define DD 64

typedef __attribute__((ext_vector_type(8))) short s16x8;
typedef __attribute__((ext_vector_type(4))) float fx4;
typedef __attribute__((ext_vector_type(8))) unsigned short u16x8;

static __device__ __forceinline__ unsigned short bf16_rne(float x) {
    union { float f; unsigned int u; } v; v.f = x;
    unsigned int u = v.u;
    u += 0x7FFFu + ((u >> 16) & 1u);
    return (unsigned short)(u >> 16);
}
static __device__ __forceinline__ float bf16_f32(unsigned short h) {
    union { unsigned int u; float f; } v; v.u = ((unsigned int)h) << 16;
    return v.f;
}

// ---------------------------------------------------------------------------
// K0: pos_vars/neg_vars = variables @ c_block[pn]^T, hi/lo bf16, tiled
// layout idx(v,d) = ((v/32)*4 + (v%32)/8)*512 + d*8 + (v%8)   (per batch)
// grid 256 blocks x 256 thr
// ---------------------------------------------------------------------------
__global__ __launch_bounds__(256) void k_prep_pv(
    const float* __restrict__ vars, const float* __restrict__ cblk,
    unsigned short* __restrict__ pvh, unsigned short* __restrict__ pvl,
    unsigned short* __restrict__ nvh, unsigned short* __restrict__ nvl)
{
    __shared__ float sv[32][64];
    __shared__ float scb[2][64][65];  // [pn][k][dout] transposed, padded
    int blk = blockIdx.x;
    int b = blk >> 6, ch = blk & 63;
    int t = threadIdx.x;
    const float* vsrc = vars + ((size_t)b * NV + (size_t)ch * 32) * DD;
    for (int i = t; i < 32 * 64; i += 256) sv[i >> 6][i & 63] = vsrc[i];
    for (int i = t; i < 2 * 64 * 64; i += 256) {
        int pn = i >> 12, dout = (i >> 6) & 63, k = i & 63;
        scb[pn][k][dout] = cblk[i];
    }
    __syncthreads();
    int ks = t >> 6, dout = t & 63;
    u16x8 vph, vpl, vnh, vnl;
    #pragma unroll
    for (int c8 = 0; c8 < 8; ++c8) {
        int vloc = ks * 8 + c8;
        float ap = 0.f, an = 0.f;
        for (int k = 0; k < 64; ++k) {
            float vv = sv[vloc][k];
            ap += vv * scb[0][k][dout];
            an += vv * scb[1][k][dout];
        }
        unsigned short h = bf16_rne(ap);
        vph[c8] = h; vpl[c8] = bf16_rne(ap - bf16_f32(h));
        h = bf16_rne(an);
        vnh[c8] = h; vnl[c8] = bf16_rne(an - bf16_f32(h));
    }
    size_t obase = (size_t)b * NV * DD + (((size_t)ch * 4 + ks) * 64 + dout) * 8;
    *(u16x8*)(pvh + obase) = vph;
    *(u16x8*)(pvl + obase) = vpl;
    *(u16x8*)(nvh + obase) = vnh;
    *(u16x8*)(nvl + obase) = vnl;
}

// ---------------------------------------------------------------------------
// K1: c_acc[b,c,d] += P@(pvh+pvl) + N@(nvh+nvl).  1-wave blocks:
// 64 clauses x 64 d, K-quarter of NV. grid 2048 x 64.
// ---------------------------------------------------------------------------
__global__ __launch_bounds__(64) void k_phaseA(
    const float* __restrict__ cmat,
    const unsigned short* __restrict__ pvh, const unsigned short* __restrict__ pvl,
    const unsigned short* __restrict__ nvh, const unsigned short* __restrict__ nvl,
    float* __restrict__ cacc)
{
    int blk = blockIdx.x;
    int b = blk >> 9;
    int rg = (blk >> 2) & 127;
    int q = blk & 3;
    int l = threadIdx.x;
    int lr = l & 15, lg = l >> 4;
    int c0 = rg * 64;
    const float* A0 = cmat + (size_t)b * NC * NV;
    const size_t pvb = (size_t)b * NV * DD;
    fx4 acc[4][4];
    #pragma unroll
    for (int i = 0; i < 4; ++i)
        #pragma unroll
        for (int j = 0; j < 4; ++j) acc[i][j] = (fx4){0.f, 0.f, 0.f, 0.f};

    #pragma unroll 1
    for (int cc = 0; cc < 16; ++cc) {
        int kc = q * 16 + cc;
        int kb = kc * 32 + lg * 8;
        s16x8 pA[4], nA[4];
        #pragma unroll
        for (int rt = 0; rt < 4; ++rt) {
            const float* src = A0 + (size_t)(c0 + rt * 16 + lr) * NV + kb;
            fx4 x0 = *(const fx4*)src;
            fx4 x1 = *(const fx4*)(src + 4);
            s16x8 p, n;
            #pragma unroll
            for (int i = 0; i < 4; ++i) {
                p[i]     = (x0[i] == 1.0f)  ? (short)0x3F80 : (short)0;
                n[i]     = (x0[i] == -1.0f) ? (short)0x3F80 : (short)0;
                p[i + 4] = (x1[i] == 1.0f)  ? (short)0x3F80 : (short)0;
                n[i + 4] = (x1[i] == -1.0f) ? (short)0x3F80 : (short)0;
            }
            pA[rt] = p; nA[rt] = n;
        }
        size_t bb = pvb + ((size_t)(kc * 4 + lg) * 64) * 8;
        s16x8 Bph[4], Bpl[4], Bnh[4], Bnl[4];
        #pragma unroll
        for (int n = 0; n < 4; ++n) {
            size_t o = bb + (size_t)(n * 16 + lr) * 8;
            Bph[n] = *(const s16x8*)(pvh + o);
            Bpl[n] = *(const s16x8*)(pvl + o);
            Bnh[n] = *(const s16x8*)(nvh + o);
            Bnl[n] = *(const s16x8*)(nvl + o);
        }
        #pragma unroll
        for (int rt = 0; rt < 4; ++rt)
            #pragma unroll
            for (int n = 0; n < 4; ++n) {
                acc[rt][n] = __builtin_amdgcn_mfma_f32_16x16x32_bf16(pA[rt], Bph[n], acc[rt][n], 0, 0, 0);
                acc[rt][n] = __builtin_amdgcn_mfma_f32_16x16x32_bf16(pA[rt], Bpl[n], acc[rt][n], 0, 0, 0);
                acc[rt][n] = __builtin_amdgcn_mfma_f32_16x16x32_bf16(nA[rt], Bnh[n], acc[rt][n], 0, 0, 0);
                acc[rt][n] = __builtin_amdgcn_mfma_f32_16x16x32_bf16(nA[rt], Bnl[n], acc[rt][n], 0, 0, 0);
            }
    }
    float* dst = cacc + ((size_t)b * NC + c0) * DD;
    #pragma unroll
    for (int rt = 0; rt < 4; ++rt)
        #pragma unroll
        for (int n = 0; n < 4; ++n)
            #pragma unroll
            for (int r = 0; r < 4; ++r)
                atomicAdd(dst + (size_t)(rt * 16 + lg * 4 + r) * DD + n * 16 + lr, acc[rt][n][r]);
}

// ---------------------------------------------------------------------------
// K2: relu(c_acc + cb) @ v_block[pn]^T -> pos/neg_cvars hi/lo, tiled (f32 math)
// grid 1024 x 256
// ---------------------------------------------------------------------------
__global__ __launch_bounds__(256) void k_projC(
    const float* __restrict__ cacc, const float* __restrict__ cb,
    const float* __restrict__ vblk,
    unsigned short* __restrict__ pch, unsigned short* __restrict__ pcl,
    unsigned short* __restrict__ nch, unsigned short* __restrict__ ncl)
{
    __shared__ float src[32][64];
    __shared__ float svb[2][64][65];
    int blk = blockIdx.x;
    int b = blk >> 8, kc = blk & 255;
    int t = threadIdx.x;
    const float* cs = cacc + ((size_t)b * NC + (size_t)kc * 32) * DD;
    for (int i = t; i < 2048; i += 256) {
        int k = i & 63;
        src[i >> 6][k] = fmaxf(cs[i] + cb[k], 0.f);
    }
    for (int i = t; i < 8192; i += 256) {
        int pn = i >> 12, dout = (i >> 6) & 63, k = i & 63;
        svb[pn][k][dout] = vblk[i];
    }
    __syncthreads();
    int ks = t >> 6, dout = t & 63;
    float ap[8] = {0.f, 0.f, 0.f, 0.f, 0.f, 0.f, 0.f, 0.f};
    float an[8] = {0.f, 0.f, 0.f, 0.f, 0.f, 0.f, 0.f, 0.f};
    for (int k = 0; k < 64; ++k) {
        float w0 = svb[0][k][dout], w1 = svb[1][k][dout];
        #pragma unroll
        for (int c8 = 0; c8 < 8; ++c8) {
            float rc = src[ks * 8 + c8][k];
            ap[c8] += rc * w0;
            an[c8] += rc * w1;
        }
    }
    u16x8 vph, vpl, vnh, vnl;
    #pragma unroll
    for (int c8 = 0; c8 < 8; ++c8) {
        unsigned short h = bf16_rne(ap[c8]);
        vph[c8] = h; vpl[c8] = bf16_rne(ap[c8] - bf16_f32(h));
        h = bf16_rne(an[c8]);
        vnh[c8] = h; vnl[c8] = bf16_rne(an[c8] - bf16_f32(h));
    }
    size_t obase = (size_t)b * NC * DD + (((size_t)kc * 4 + ks) * 64 + dout) * 8;
    *(u16x8*)(pch + obase) = vph;
    *(u16x8*)(pcl + obase) = vpl;
    *(u16x8*)(nch + obase) = vnh;
    *(u16x8*)(ncl + obase) = vnl;
}

// ---------------------------------------------------------------------------
// K3: nv_msg += Pv@(pch+pcl) + Nv@(nch+ncl) over v_mat. 1-wave blocks:
// 64 vars x 64 d, K-eighth of NC. grid 1024 x 64.
// ---------------------------------------------------------------------------
__global__ __launch_bounds__(64) void k_phaseB(
    const float* __restrict__ vmat,
    const unsigned short* __restrict__ pch, const unsigned short* __restrict__ pcl,
    const unsigned short* __restrict__ nch, const unsigned short* __restrict__ ncl,
    float* __restrict__ nvmsg)
{
    int blk = blockIdx.x;
    int b = blk >> 8;
    int rg = (blk >> 3) & 31;
    int q = blk & 7;
    int l = threadIdx.x;
    int lr = l & 15, lg = l >> 4;
    int v0 = rg * 64;
    const float* A0 = vmat + (size_t)b * NV * NC;
    const size_t cvb = (size_t)b * NC * DD;
    fx4 acc[4][4];
    #pragma unroll
    for (int i = 0; i < 4; ++i)
        #pragma unroll
        for (int j = 0; j < 4; ++j) acc[i][j] = (fx4){0.f, 0.f, 0.f, 0.f};

    #pragma unroll 1
    for (int cc = 0; cc < 32; ++cc) {
        int kc = q * 32 + cc;
        int kb = kc * 32 + lg * 8;
        s16x8 pA[4], nA[4];
        #pragma unroll
        for (int rt = 0; rt < 4; ++rt) {
            const float* src = A0 + (size_t)(v0 + rt * 16 + lr) * NC + kb;
            fx4 x0 = *(const fx4*)src;
            fx4 x1 = *(const fx4*)(src + 4);
            s16x8 p, n;
            #pragma unroll
            for (int i = 0; i < 4; ++i) {
                p[i]     = (x0[i] == 1.0f)  ? (short)0x3F80 : (short)0;
                n[i]     = (x0[i] == -1.0f) ? (short)0x3F80 : (short)0;
                p[i + 4] = (x1[i] == 1.0f)  ? (short)0x3F80 : (short)0;
                n[i + 4] = (x1[i] == -1.0f) ? (short)0x3F80 : (short)0;
            }
            pA[rt] = p; nA[rt] = n;
        }
        size_t bb = cvb + ((size_t)(kc * 4 + lg) * 64) * 8;
        s16x8 Bph[4], Bpl[4], Bnh[4], Bnl[4];
        #pragma unroll
        for (int n = 0; n < 4; ++n) {
            size_t o = bb + (size_t)(n * 16 + lr) * 8;
            Bph[n] = *(const s16x8*)(pch + o);
            Bpl[n] = *(const s16x8*)(pcl + o);
            Bnh[n] = *(const s16x8*)(nch + o);
            Bnl[n] = *(const s16x8*)(ncl + o);
        }
        #pragma unroll
        for (int rt = 0; rt < 4; ++rt)
            #pragma unroll
            for (int n = 0; n < 4; ++n) {
                acc[rt][n] = __builtin_amdgcn_mfma_f32_16x16x32_bf16(pA[rt], Bph[n], acc[rt][n], 0, 0, 0);
                acc[rt][n] = __builtin_amdgcn_mfma_f32_16x16x32_bf16(pA[rt], Bpl[n], acc[rt][n], 0, 0, 0);
                acc[rt][n] = __builtin_amdgcn_mfma_f32_16x16x32_bf16(nA[rt], Bnh[n], acc[rt][n], 0, 0, 0);
                acc[rt][n] = __builtin_amdgcn_mfma_f32_16x16x32_bf16(nA[rt], Bnl[n], acc[rt][n], 0, 0, 0);
            }
    }
    float* dst = nvmsg + ((size_t)b * NV + v0) * DD;
    #pragma unroll
    for (int rt = 0; rt < 4; ++rt)
        #pragma unroll
        for (int n = 0; n < 4; ++n)
            #pragma unroll
            for (int r = 0; r < 4; ++r)
                atomicAdd(dst + (size_t)(rt * 16 + lg * 4 + r) * DD + n * 16 + lr, acc[rt][n][r]);
}

// ---------------------------------------------------------------------------
// K4: v_emb=relu(nv_msg+vb); av=tanh([g|v_emb]@Wg^T+bg); GRU -> out (all f32)
// 8 rows/block, 512 thr, weights transposed in LDS. grid 1024 x 512.
// ---------------------------------------------------------------------------
__global__ __launch_bounds__(512) void k_gru(
    const float* __restrict__ nvmsg, const float* __restrict__ vars,
    const float* __restrict__ gv, const float* __restrict__ vb,
    const float* __restrict__ Wg, const float* __restrict__ bg,
    const float* __restrict__ Wz, const float* __restrict__ Uz, const float* __restrict__ bz,
    const float* __restrict__ Wr, const float* __restrict__ Ur, const float* __restrict__ brr,
    const float* __restrict__ Wh, const float* __restrict__ Uh, const float* __restrict__ bh,
    float* __restrict__ out)
{
    __shared__ float sWg[72][65];
    __shared__ float sWz[64][65], sUz[64][65];
    __shared__ float sWr[64][65], sUr[64][65];
    __shared__ float sWh[64][65], sUh[64][65];
    __shared__ float scat[8][72];
    __shared__ float sprev[8][64];
    __shared__ float sav[8][64];
    __shared__ float srp[8][64];
    int t = threadIdx.x;
    for (int i = t; i < 64 * 72; i += 512) {
        int dout = i / 72, j = i - dout * 72;
        sWg[j][dout] = Wg[i];
    }
    for (int i = t; i < 4096; i += 512) {
        int dout = i >> 6, k = i & 63;
        sWz[k][dout] = Wz[i]; sUz[k][dout] = Uz[i];
        sWr[k][dout] = Wr[i]; sUr[k][dout] = Ur[i];
        sWh[k][dout] = Wh[i]; sUh[k][dout] = Uh[i];
    }
    int rr = t >> 6, dout = t & 63;
    size_t row = (size_t)blockIdx.x * 8 + rr;
    float prev = vars[row * 64 + dout];
    float ve = fmaxf(nvmsg[row * 64 + dout] + vb[dout], 0.f);
    scat[rr][8 + dout] = ve;
    if (dout < 8) scat[rr][dout] = gv[row * 8 + dout];
    sprev[rr][dout] = prev;
    __syncthreads();
    float a = bg[dout];
    for (int j = 0; j < 72; ++j) a += scat[rr][j] * sWg[j][dout];
    float av = 1.f - 2.f / (__expf(2.f * a) + 1.f);
    sav[rr][dout] = av;
    __syncthreads();
    float zi = bz[dout], ri = brr[dout], hwa = 0.f;
    for (int k = 0; k < 64; ++k) {
        float ak = sav[rr][k], pk = sprev[rr][k];
        zi += ak * sWz[k][dout] + pk * sUz[k][dout];
        ri += ak * sWr[k][dout] + pk * sUr[k][dout];
        hwa += ak * sWh[k][dout];
    }
    float z = 1.f / (1.f + __expf(-zi));
    float rgate = 1.f / (1.f + __expf(-ri));
    srp[rr][dout] = rgate * prev;
    __syncthreads();
    float hin = bh[dout] + hwa;
    for (int k = 0; k < 64; ++k) hin += srp[rr][k] * sUh[k][dout];
    float ht = 1.f - 2.f / (__expf(2.f * hin) + 1.f);
    out[row * 64 + dout] = (1.f - z) * prev + z * ht;
}

// ---------------------------------------------------------------------------
extern "C" void kernel_launch(void* const* d_in, const int* in_sizes, int n_in,
                              void* d_out, int out_size, void* d_ws, size_t ws_size,
                              hipStream_t stream) {
    (void)in_sizes; (void)n_in; (void)out_size; (void)ws_size;
    const float* vars = (const float*)d_in[0];
    const float* gv   = (const float*)d_in[1];
    const float* cmat = (const float*)d_in[2];
    const float* vmat = (const float*)d_in[3];
    const float* cblk = (const float*)d_in[4];
    const float* vblk = (const float*)d_in[5];
    const float* vb   = (const float*)d_in[6];
    const float* cb   = (const float*)d_in[7];
    const float* Wg   = (const float*)d_in[8];
    const float* bg   = (const float*)d_in[9];
    const float* Wz   = (const float*)d_in[10];
    const float* Uz   = (const float*)d_in[11];
    const float* bz   = (const float*)d_in[12];
    const float* Wr   = (const float*)d_in[13];
    const float* Ur   = (const float*)d_in[14];
    const float* br_  = (const float*)d_in[15];
    const float* Wh   = (const float*)d_in[16];
    const float* Uh   = (const float*)d_in[17];
    const float* bh   = (const float*)d_in[18];
    float* out = (float*)d_out;

    char* w = (char*)d_ws;
    const size_t szPV = (size_t)NBATCH * NV * DD * 2;  // 1 MB
    const size_t szCV = (size_t)NBATCH * NC * DD * 2;  // 4 MB
    unsigned short* pvh = (unsigned short*)(w);
    unsigned short* pvl = (unsigned short*)(w + szPV);
    unsigned short* nvh = (unsigned short*)(w + 2 * szPV);
    unsigned short* nvl = (unsigned short*)(w + 3 * szPV);
    unsigned short* pch = (unsigned short*)(w + 4 * szPV);
    unsigned short* pcl = (unsigned short*)(w + 4 * szPV + szCV);
    unsigned short* nch = (unsigned short*)(w + 4 * szPV + 2 * szCV);
    unsigned short* ncl = (unsigned short*)(w + 4 * szPV + 3 * szCV);
    float* cacc  = (float*)(w + 4 * szPV + 4 * szCV);                       // 8 MB
    float* nvmsg = (float*)(w + 4 * szPV + 4 * szCV + (size_t)NBATCH * NC * DD * 4);  // 2 MB

    hipMemsetAsync(cacc, 0, (size_t)NBATCH * NC * DD * 4, stream);
    hipMemsetAsync(nvmsg, 0, (size_t)NBATCH * NV * DD * 4, stream);

    k_prep_pv<<<256, 256, 0, stream>>>(vars, cblk, pvh, pvl, nvh, nvl);
    k_phaseA<<<2048, 64, 0, stream>>>(cmat, pvh, pvl, nvh, nvl, cacc);
    k_projC<<<1024, 256, 0, stream>>>(cacc, cb, vblk, pch, pcl, nch, ncl);
    k_phaseB<<<1024, 64, 0, stream>>>(vmat, pch, pcl, nch, ncl, nvmsg);
    k_gru<<<1024, 512, 0, stream>>>(nvmsg, vars, gv, vb, Wg, bg,
                                    Wz, Uz, bz, Wr, Ur, br_, Wh, Uh, bh, out);
}

// Round 2
// 217.745 us; speedup vs baseline: 1.2655x; 1.2655x over previous
//
#include <hip/hip_runtime.h>
#include <hip/hip_bf16.h>
#include <stdint.h>

#define NBATCH 4
#define NV 2048
#define NC 8192
#define DD 64

typedef __attribute__((ext_vector_type(8))) short s16x8;
typedef __attribute__((ext_vector_type(4))) float fx4;
typedef __attribute__((ext_vector_type(8))) unsigned short u16x8;
typedef __attribute__((ext_vector_type(4))) unsigned int u32x4;

static __device__ __forceinline__ unsigned short bf16_rne(float x) {
    union { float f; unsigned int u; } v; v.f = x;
    unsigned int u = v.u;
    u += 0x7FFFu + ((u >> 16) & 1u);
    return (unsigned short)(u >> 16);
}
static __device__ __forceinline__ float bf16_f32(unsigned short h) {
    union { unsigned int u; float f; } v; v.u = ((unsigned int)h) << 16;
    return v.f;
}
// pack bf16(a) into low16, bf16(b) into high16 (a,b are exactly-representable {0,1})
static __device__ __forceinline__ unsigned int pack_hi(float a, float b) {
    return (__builtin_bit_cast(unsigned int, a) >> 16) |
           (__builtin_bit_cast(unsigned int, b) & 0xFFFF0000u);
}

// ---------------------------------------------------------------------------
// K0: pos_vars/neg_vars = variables @ c_block[pn]^T, hi/lo bf16, tiled
// layout idx(v,d) = ((v/32)*4 + (v%32)/8)*512 + d*8 + (v%8)   (per batch)
// ---------------------------------------------------------------------------
__global__ __launch_bounds__(256) void k_prep_pv(
    const float* __restrict__ vars, const float* __restrict__ cblk,
    unsigned short* __restrict__ pvh, unsigned short* __restrict__ pvl,
    unsigned short* __restrict__ nvh, unsigned short* __restrict__ nvl)
{
    __shared__ float sv[32][64];
    __shared__ float scb[2][64][65];
    int blk = blockIdx.x;
    int b = blk >> 6, ch = blk & 63;
    int t = threadIdx.x;
    const float* vsrc = vars + ((size_t)b * NV + (size_t)ch * 32) * DD;
    for (int i = t; i < 32 * 64; i += 256) sv[i >> 6][i & 63] = vsrc[i];
    for (int i = t; i < 2 * 64 * 64; i += 256) {
        int pn = i >> 12, dout = (i >> 6) & 63, k = i & 63;
        scb[pn][k][dout] = cblk[i];
    }
    __syncthreads();
    int ks = t >> 6, dout = t & 63;
    u16x8 vph, vpl, vnh, vnl;
    #pragma unroll
    for (int c8 = 0; c8 < 8; ++c8) {
        int vloc = ks * 8 + c8;
        float ap = 0.f, an = 0.f;
        for (int k = 0; k < 64; ++k) {
            float vv = sv[vloc][k];
            ap += vv * scb[0][k][dout];
            an += vv * scb[1][k][dout];
        }
        unsigned short h = bf16_rne(ap);
        vph[c8] = h; vpl[c8] = bf16_rne(ap - bf16_f32(h));
        h = bf16_rne(an);
        vnh[c8] = h; vnl[c8] = bf16_rne(an - bf16_f32(h));
    }
    size_t obase = (size_t)b * NV * DD + (((size_t)ch * 4 + ks) * 64 + dout) * 8;
    *(u16x8*)(pvh + obase) = vph;
    *(u16x8*)(pvl + obase) = vpl;
    *(u16x8*)(nvh + obase) = vnh;
    *(u16x8*)(nvl + obase) = vnl;
}

// ---------------------------------------------------------------------------
// K1: cpart[q][b][c][d] = P@(pvh+pvl) + N@(nvh+nvl) over K-quarter q.
// Also emits comp[b][v8][c] 2-bit codes ((int)x & 3) for phase B.
// grid 2048 x 64 (1 wave / block), no atomics, no zero-init needed.
// ---------------------------------------------------------------------------
__global__ __launch_bounds__(64) void k_phaseA(
    const float* __restrict__ cmat,
    const unsigned short* __restrict__ pvh, const unsigned short* __restrict__ pvl,
    const unsigned short* __restrict__ nvh, const unsigned short* __restrict__ nvl,
    float* __restrict__ cpart, unsigned short* __restrict__ comp)
{
    int blk = blockIdx.x;
    int b = blk >> 9;
    int rg = (blk >> 2) & 127;
    int q = blk & 3;
    int l = threadIdx.x;
    int lr = l & 15, lg = l >> 4;
    int c0 = rg * 64;
    const float* A0 = cmat + (size_t)b * NC * NV;
    const size_t pvb = (size_t)b * NV * DD;
    unsigned short* compb = comp + (size_t)b * 256 * NC;
    fx4 acc[4][4];
    #pragma unroll
    for (int i = 0; i < 4; ++i)
        #pragma unroll
        for (int j = 0; j < 4; ++j) acc[i][j] = (fx4){0.f, 0.f, 0.f, 0.f};

    #pragma unroll 1
    for (int cc = 0; cc < 16; ++cc) {
        int kc = q * 16 + cc;
        int kb = kc * 32 + lg * 8;
        s16x8 pA[4], nA[4];
        #pragma unroll
        for (int rt = 0; rt < 4; ++rt) {
            const float* src = A0 + (size_t)(c0 + rt * 16 + lr) * NV + kb;
            fx4 x0 = *(const fx4*)src;
            fx4 x1 = *(const fx4*)(src + 4);
            // indicator bf16 frags via exact high-16 packing of {0,1} floats
            u32x4 pw, nw;
            pw[0] = pack_hi(fmaxf(x0[0], 0.f), fmaxf(x0[1], 0.f));
            pw[1] = pack_hi(fmaxf(x0[2], 0.f), fmaxf(x0[3], 0.f));
            pw[2] = pack_hi(fmaxf(x1[0], 0.f), fmaxf(x1[1], 0.f));
            pw[3] = pack_hi(fmaxf(x1[2], 0.f), fmaxf(x1[3], 0.f));
            nw[0] = pack_hi(fmaxf(-x0[0], 0.f), fmaxf(-x0[1], 0.f));
            nw[1] = pack_hi(fmaxf(-x0[2], 0.f), fmaxf(-x0[3], 0.f));
            nw[2] = pack_hi(fmaxf(-x1[0], 0.f), fmaxf(-x1[1], 0.f));
            nw[3] = pack_hi(fmaxf(-x1[2], 0.f), fmaxf(-x1[3], 0.f));
            pA[rt] = __builtin_bit_cast(s16x8, pw);
            nA[rt] = __builtin_bit_cast(s16x8, nw);
            // 2-bit codes for phase B: (int)x & 3 -> {0,1,3}
            unsigned int t0 = ((int)x0[0]) & 3, t1 = ((int)x0[1]) & 3;
            unsigned int t2 = ((int)x0[2]) & 3, t3 = ((int)x0[3]) & 3;
            unsigned int t4 = ((int)x1[0]) & 3, t5 = ((int)x1[1]) & 3;
            unsigned int t6 = ((int)x1[2]) & 3, t7 = ((int)x1[3]) & 3;
            unsigned int bits = (t0 | (t1 << 2)) | ((t2 | (t3 << 2)) << 4)
                              | ((t4 | (t5 << 2)) << 8) | ((t6 | (t7 << 2)) << 12);
            compb[(size_t)(kc * 4 + lg) * NC + (c0 + rt * 16 + lr)] = (unsigned short)bits;
        }
        size_t bb = pvb + ((size_t)(kc * 4 + lg) * 64) * 8;
        s16x8 Bph[4], Bpl[4], Bnh[4], Bnl[4];
        #pragma unroll
        for (int n = 0; n < 4; ++n) {
            size_t o = bb + (size_t)(n * 16 + lr) * 8;
            Bph[n] = *(const s16x8*)(pvh + o);
            Bpl[n] = *(const s16x8*)(pvl + o);
            Bnh[n] = *(const s16x8*)(nvh + o);
            Bnl[n] = *(const s16x8*)(nvl + o);
        }
        #pragma unroll
        for (int rt = 0; rt < 4; ++rt)
            #pragma unroll
            for (int n = 0; n < 4; ++n) {
                acc[rt][n] = __builtin_amdgcn_mfma_f32_16x16x32_bf16(pA[rt], Bph[n], acc[rt][n], 0, 0, 0);
                acc[rt][n] = __builtin_amdgcn_mfma_f32_16x16x32_bf16(pA[rt], Bpl[n], acc[rt][n], 0, 0, 0);
                acc[rt][n] = __builtin_amdgcn_mfma_f32_16x16x32_bf16(nA[rt], Bnh[n], acc[rt][n], 0, 0, 0);
                acc[rt][n] = __builtin_amdgcn_mfma_f32_16x16x32_bf16(nA[rt], Bnl[n], acc[rt][n], 0, 0, 0);
            }
    }
    float* dst = cpart + (((size_t)q * NBATCH + b) * NC + c0) * DD;
    #pragma unroll
    for (int rt = 0; rt < 4; ++rt)
        #pragma unroll
        for (int n = 0; n < 4; ++n)
            #pragma unroll
            for (int r = 0; r < 4; ++r)
                dst[(size_t)(rt * 16 + lg * 4 + r) * DD + n * 16 + lr] = acc[rt][n][r];
}

// ---------------------------------------------------------------------------
// K2: relu(sum_q cpart + cb) @ v_block[pn]^T -> pos/neg_cvars hi/lo, tiled
// grid 1024 x 256
// ---------------------------------------------------------------------------
__global__ __launch_bounds__(256) void k_projC(
    const float* __restrict__ cpart, const float* __restrict__ cb,
    const float* __restrict__ vblk,
    unsigned short* __restrict__ pch, unsigned short* __restrict__ pcl,
    unsigned short* __restrict__ nch, unsigned short* __restrict__ ncl)
{
    __shared__ float src[32][64];
    __shared__ float svb[2][64][65];
    int blk = blockIdx.x;
    int b = blk >> 8, kc = blk & 255;
    int t = threadIdx.x;
    const size_t qs = (size_t)NBATCH * NC * DD;
    const float* cs = cpart + ((size_t)b * NC + (size_t)kc * 32) * DD;
    for (int i = t; i < 2048; i += 256) {
        int k = i & 63;
        float v = cs[i] + cs[i + qs] + cs[i + 2 * qs] + cs[i + 3 * qs] + cb[k];
        src[i >> 6][k] = fmaxf(v, 0.f);
    }
    for (int i = t; i < 8192; i += 256) {
        int pn = i >> 12, dout = (i >> 6) & 63, k = i & 63;
        svb[pn][k][dout] = vblk[i];
    }
    __syncthreads();
    int ks = t >> 6, dout = t & 63;
    float ap[8] = {0.f, 0.f, 0.f, 0.f, 0.f, 0.f, 0.f, 0.f};
    float an[8] = {0.f, 0.f, 0.f, 0.f, 0.f, 0.f, 0.f, 0.f};
    for (int k = 0; k < 64; ++k) {
        float w0 = svb[0][k][dout], w1 = svb[1][k][dout];
        #pragma unroll
        for (int c8 = 0; c8 < 8; ++c8) {
            float rc = src[ks * 8 + c8][k];
            ap[c8] += rc * w0;
            an[c8] += rc * w1;
        }
    }
    u16x8 vph, vpl, vnh, vnl;
    #pragma unroll
    for (int c8 = 0; c8 < 8; ++c8) {
        unsigned short h = bf16_rne(ap[c8]);
        vph[c8] = h; vpl[c8] = bf16_rne(ap[c8] - bf16_f32(h));
        h = bf16_rne(an[c8]);
        vnh[c8] = h; vnl[c8] = bf16_rne(an[c8] - bf16_f32(h));
    }
    size_t obase = (size_t)b * NC * DD + (((size_t)kc * 4 + ks) * 64 + dout) * 8;
    *(u16x8*)(pch + obase) = vph;
    *(u16x8*)(pcl + obase) = vpl;
    *(u16x8*)(nch + obase) = vnh;
    *(u16x8*)(ncl + obase) = vnl;
}

// ---------------------------------------------------------------------------
// K3: npart[q][b][v][d] = Pv@(pch+pcl) + Nv@(nch+ncl), adjacency decoded from
// comp 2-bit codes (code==1 -> pos, code==3 -> neg). grid 1024 x 64.
// ---------------------------------------------------------------------------
__global__ __launch_bounds__(64) void k_phaseB(
    const unsigned short* __restrict__ comp,
    const unsigned short* __restrict__ pch, const unsigned short* __restrict__ pcl,
    const unsigned short* __restrict__ nch, const unsigned short* __restrict__ ncl,
    float* __restrict__ npart)
{
    int blk = blockIdx.x;
    int b = blk >> 8;
    int rg = (blk >> 3) & 31;
    int q = blk & 7;
    int l = threadIdx.x;
    int lr = l & 15, lg = l >> 4;
    int v0 = rg * 64;
    const unsigned short* compb = comp + (size_t)b * 256 * NC;
    const size_t cvb = (size_t)b * NC * DD;
    int sh = 2 * (lr & 7);
    fx4 acc[4][4];
    #pragma unroll
    for (int i = 0; i < 4; ++i)
        #pragma unroll
        for (int j = 0; j < 4; ++j) acc[i][j] = (fx4){0.f, 0.f, 0.f, 0.f};

    #pragma unroll 1
    for (int cc = 0; cc < 32; ++cc) {
        int kc = q * 32 + cc;
        int kb = kc * 32 + lg * 8;
        s16x8 pA[4], nA[4];
        #pragma unroll
        for (int rt = 0; rt < 4; ++rt) {
            int v8 = (v0 + rt * 16 + lr) >> 3;
            u16x8 u = *(const u16x8*)(compb + (size_t)v8 * NC + kb);
            s16x8 p, n;
            #pragma unroll
            for (int i = 0; i < 8; ++i) {
                unsigned int s = ((unsigned int)u[i] >> sh) & 3u;
                p[i] = (s == 1u) ? (short)0x3F80 : (short)0;
                n[i] = (s == 3u) ? (short)0x3F80 : (short)0;
            }
            pA[rt] = p; nA[rt] = n;
        }
        size_t bb = cvb + ((size_t)(kc * 4 + lg) * 64) * 8;
        s16x8 Bph[4], Bpl[4], Bnh[4], Bnl[4];
        #pragma unroll
        for (int n = 0; n < 4; ++n) {
            size_t o = bb + (size_t)(n * 16 + lr) * 8;
            Bph[n] = *(const s16x8*)(pch + o);
            Bpl[n] = *(const s16x8*)(pcl + o);
            Bnh[n] = *(const s16x8*)(nch + o);
            Bnl[n] = *(const s16x8*)(ncl + o);
        }
        #pragma unroll
        for (int rt = 0; rt < 4; ++rt)
            #pragma unroll
            for (int n = 0; n < 4; ++n) {
                acc[rt][n] = __builtin_amdgcn_mfma_f32_16x16x32_bf16(pA[rt], Bph[n], acc[rt][n], 0, 0, 0);
                acc[rt][n] = __builtin_amdgcn_mfma_f32_16x16x32_bf16(pA[rt], Bpl[n], acc[rt][n], 0, 0, 0);
                acc[rt][n] = __builtin_amdgcn_mfma_f32_16x16x32_bf16(nA[rt], Bnh[n], acc[rt][n], 0, 0, 0);
                acc[rt][n] = __builtin_amdgcn_mfma_f32_16x16x32_bf16(nA[rt], Bnl[n], acc[rt][n], 0, 0, 0);
            }
    }
    float* dst = npart + (((size_t)q * NBATCH + b) * NV + v0) * DD;
    #pragma unroll
    for (int rt = 0; rt < 4; ++rt)
        #pragma unroll
        for (int n = 0; n < 4; ++n)
            #pragma unroll
            for (int r = 0; r < 4; ++r)
                dst[(size_t)(rt * 16 + lg * 4 + r) * DD + n * 16 + lr] = acc[rt][n][r];
}

// ---------------------------------------------------------------------------
// K4: v_emb=relu(sum_q npart+vb); av=tanh([g|v_emb]@Wg^T+bg); GRU -> out (f32)
// ---------------------------------------------------------------------------
__global__ __launch_bounds__(512) void k_gru(
    const float* __restrict__ npart, const float* __restrict__ vars,
    const float* __restrict__ gv, const float* __restrict__ vb,
    const float* __restrict__ Wg, const float* __restrict__ bg,
    const float* __restrict__ Wz, const float* __restrict__ Uz, const float* __restrict__ bz,
    const float* __restrict__ Wr, const float* __restrict__ Ur, const float* __restrict__ brr,
    const float* __restrict__ Wh, const float* __restrict__ Uh, const float* __restrict__ bh,
    float* __restrict__ out)
{
    __shared__ float sWg[72][65];
    __shared__ float sWz[64][65], sUz[64][65];
    __shared__ float sWr[64][65], sUr[64][65];
    __shared__ float sWh[64][65], sUh[64][65];
    __shared__ float scat[8][72];
    __shared__ float sprev[8][64];
    __shared__ float sav[8][64];
    __shared__ float srp[8][64];
    int t = threadIdx.x;
    for (int i = t; i < 64 * 72; i += 512) {
        int dout = i / 72, j = i - dout * 72;
        sWg[j][dout] = Wg[i];
    }
    for (int i = t; i < 4096; i += 512) {
        int dout = i >> 6, k = i & 63;
        sWz[k][dout] = Wz[i]; sUz[k][dout] = Uz[i];
        sWr[k][dout] = Wr[i]; sUr[k][dout] = Ur[i];
        sWh[k][dout] = Wh[i]; sUh[k][dout] = Uh[i];
    }
    int rr = t >> 6, dout = t & 63;
    size_t row = (size_t)blockIdx.x * 8 + rr;
    float prev = vars[row * 64 + dout];
    float ve = vb[dout];
    const size_t qs = (size_t)NBATCH * NV * DD;
    #pragma unroll
    for (int s = 0; s < 8; ++s) ve += npart[(size_t)s * qs + row * 64 + dout];
    ve = fmaxf(ve, 0.f);
    scat[rr][8 + dout] = ve;
    if (dout < 8) scat[rr][dout] = gv[row * 8 + dout];
    sprev[rr][dout] = prev;
    __syncthreads();
    float a = bg[dout];
    for (int j = 0; j < 72; ++j) a += scat[rr][j] * sWg[j][dout];
    float av = 1.f - 2.f / (__expf(2.f * a) + 1.f);
    sav[rr][dout] = av;
    __syncthreads();
    float zi = bz[dout], ri = brr[dout], hwa = 0.f;
    for (int k = 0; k < 64; ++k) {
        float ak = sav[rr][k], pk = sprev[rr][k];
        zi += ak * sWz[k][dout] + pk * sUz[k][dout];
        ri += ak * sWr[k][dout] + pk * sUr[k][dout];
        hwa += ak * sWh[k][dout];
    }
    float z = 1.f / (1.f + __expf(-zi));
    float rgate = 1.f / (1.f + __expf(-ri));
    srp[rr][dout] = rgate * prev;
    __syncthreads();
    float hin = bh[dout] + hwa;
    for (int k = 0; k < 64; ++k) hin += srp[rr][k] * sUh[k][dout];
    float ht = 1.f - 2.f / (__expf(2.f * hin) + 1.f);
    out[row * 64 + dout] = (1.f - z) * prev + z * ht;
}

// ---------------------------------------------------------------------------
extern "C" void kernel_launch(void* const* d_in, const int* in_sizes, int n_in,
                              void* d_out, int out_size, void* d_ws, size_t ws_size,
                              hipStream_t stream) {
    (void)in_sizes; (void)n_in; (void)out_size; (void)ws_size;
    const float* vars = (const float*)d_in[0];
    const float* gv   = (const float*)d_in[1];
    const float* cmat = (const float*)d_in[2];
    const float* vblk = (const float*)d_in[5];
    const float* cblk = (const float*)d_in[4];
    const float* vb   = (const float*)d_in[6];
    const float* cb   = (const float*)d_in[7];
    const float* Wg   = (const float*)d_in[8];
    const float* bg   = (const float*)d_in[9];
    const float* Wz   = (const float*)d_in[10];
    const float* Uz   = (const float*)d_in[11];
    const float* bz   = (const float*)d_in[12];
    const float* Wr   = (const float*)d_in[13];
    const float* Ur   = (const float*)d_in[14];
    const float* br_  = (const float*)d_in[15];
    const float* Wh   = (const float*)d_in[16];
    const float* Uh   = (const float*)d_in[17];
    const float* bh   = (const float*)d_in[18];
    float* out = (float*)d_out;

    char* w = (char*)d_ws;
    const size_t MB = 1024 * 1024;
    unsigned short* pvh = (unsigned short*)(w + 0 * MB);
    unsigned short* pvl = (unsigned short*)(w + 1 * MB);
    unsigned short* nvh = (unsigned short*)(w + 2 * MB);
    unsigned short* nvl = (unsigned short*)(w + 3 * MB);
    unsigned short* pch = (unsigned short*)(w + 4 * MB);
    unsigned short* pcl = (unsigned short*)(w + 8 * MB);
    unsigned short* nch = (unsigned short*)(w + 12 * MB);
    unsigned short* ncl = (unsigned short*)(w + 16 * MB);
    float* cpart        = (float*)(w + 20 * MB);          // 32 MB: [4][B][NC][DD]
    float* npart        = (float*)(w + 52 * MB);          // 16 MB: [8][B][NV][DD]
    unsigned short* comp = (unsigned short*)(w + 68 * MB); // 16 MB: [B][256][NC]

    k_prep_pv<<<256, 256, 0, stream>>>(vars, cblk, pvh, pvl, nvh, nvl);
    k_phaseA<<<2048, 64, 0, stream>>>(cmat, pvh, pvl, nvh, nvl, cpart, comp);
    k_projC<<<1024, 256, 0, stream>>>(cpart, cb, vblk, pch, pcl, nch, ncl);
    k_phaseB<<<1024, 64, 0, stream>>>(comp, pch, pcl, nch, ncl, npart);
    k_gru<<<1024, 512, 0, stream>>>(npart, vars, gv, vb, Wg, bg,
                                    Wz, Uz, bz, Wr, Ur, br_, Wh, Uh, bh, out);
}

// Round 3
// 197.097 us; speedup vs baseline: 1.3981x; 1.1048x over previous
//
#include <hip/hip_runtime.h>
#include <hip/hip_bf16.h>
#include <stdint.h>

#define NBATCH 4
#define NV 2048
#define NC 8192
#define DD 64

typedef __attribute__((ext_vector_type(8))) short s16x8;
typedef __attribute__((ext_vector_type(4))) float fx4;
typedef __attribute__((ext_vector_type(8))) unsigned short u16x8;
typedef __attribute__((ext_vector_type(4))) unsigned int u32x4;

static __device__ __forceinline__ unsigned short bf16_rne(float x) {
    union { float f; unsigned int u; } v; v.f = x;
    unsigned int u = v.u;
    u += 0x7FFFu + ((u >> 16) & 1u);
    return (unsigned short)(u >> 16);
}
static __device__ __forceinline__ float bf16_f32(unsigned short h) {
    union { unsigned int u; float f; } v; v.u = ((unsigned int)h) << 16;
    return v.f;
}
// pack high16(a) into low half, high16(b) into high half (exact for {0,±1})
static __device__ __forceinline__ unsigned int packhi2(float a, float b) {
    return __builtin_amdgcn_perm(__builtin_bit_cast(unsigned int, b),
                                 __builtin_bit_cast(unsigned int, a), 0x07060302u);
}

// ---------------------------------------------------------------------------
// K0: s=(pos+neg)/2, d=(pos-neg)/2 of variables @ c_block[pn]^T, hi/lo bf16,
// tiled B-frag layout idx(v,dout) = ((v/8)*64 + dout)*8 + (v%8)  (per batch)
// ---------------------------------------------------------------------------
__global__ __launch_bounds__(256) void k_prep_pv(
    const float* __restrict__ vars, const float* __restrict__ cblk,
    unsigned short* __restrict__ bsh, unsigned short* __restrict__ bsl,
    unsigned short* __restrict__ bdh, unsigned short* __restrict__ bdl)
{
    __shared__ float sv[32][64];
    __shared__ float scb[2][64][65];
    int blk = blockIdx.x;
    int b = blk >> 6, ch = blk & 63;
    int t = threadIdx.x;
    const float* vsrc = vars + ((size_t)b * NV + (size_t)ch * 32) * DD;
    for (int i = t; i < 32 * 64; i += 256) sv[i >> 6][i & 63] = vsrc[i];
    for (int i = t; i < 2 * 64 * 64; i += 256) {
        int pn = i >> 12, dout = (i >> 6) & 63, k = i & 63;
        scb[pn][k][dout] = cblk[i];
    }
    __syncthreads();
    int ks = t >> 6, dout = t & 63;
    u16x8 vsh, vsl, vdh, vdl;
    #pragma unroll
    for (int c8 = 0; c8 < 8; ++c8) {
        int vloc = ks * 8 + c8;
        float ap = 0.f, an = 0.f;
        for (int k = 0; k < 64; ++k) {
            float vv = sv[vloc][k];
            ap += vv * scb[0][k][dout];
            an += vv * scb[1][k][dout];
        }
        float s = (ap + an) * 0.5f, dv = (ap - an) * 0.5f;
        unsigned short h = bf16_rne(s);
        vsh[c8] = h; vsl[c8] = bf16_rne(s - bf16_f32(h));
        h = bf16_rne(dv);
        vdh[c8] = h; vdl[c8] = bf16_rne(dv - bf16_f32(h));
    }
    size_t obase = (size_t)b * NV * DD + (((size_t)ch * 4 + ks) * 64 + dout) * 8;
    *(u16x8*)(bsh + obase) = vsh;
    *(u16x8*)(bsl + obase) = vsl;
    *(u16x8*)(bdh + obase) = vdh;
    *(u16x8*)(bdl + obase) = vdl;
}

// ---------------------------------------------------------------------------
// K1: cpart[q][b][c][d] = |A|@(bsh+bsl) + A@(bdh+bdl) over K-eighth q.
// Emits comp[b][kslot][c] 2-bit codes. grid 4096 x 64, depth-1 A-prefetch.
// ---------------------------------------------------------------------------
__global__ __launch_bounds__(64, 2) void k_phaseA(
    const float* __restrict__ cmat,
    const unsigned short* __restrict__ bsh, const unsigned short* __restrict__ bsl,
    const unsigned short* __restrict__ bdh, const unsigned short* __restrict__ bdl,
    float* __restrict__ cpart, unsigned short* __restrict__ comp)
{
    int blk = blockIdx.x;
    int q = blk & 7;             // low bits -> XCD-local B working set
    int rg = (blk >> 3) & 127;
    int b = blk >> 10;
    int l = threadIdx.x;
    int lr = l & 15, lg = l >> 4;
    int c0 = rg * 64;
    const float* A0 = cmat + (size_t)b * NC * NV + (size_t)lr * NV
                    + (size_t)(q * 8) * 32 + lg * 8;
    const size_t pvb = (size_t)b * NV * DD;
    unsigned short* compb = comp + (size_t)b * 256 * NC;
    fx4 acc[4][4];
    #pragma unroll
    for (int i = 0; i < 4; ++i)
        #pragma unroll
        for (int j = 0; j < 4; ++j) acc[i][j] = (fx4){0.f, 0.f, 0.f, 0.f};

    fx4 xc0[4], xc1[4];
    #pragma unroll
    for (int rt = 0; rt < 4; ++rt) {
        const float* src = A0 + (size_t)(c0 + rt * 16) * NV;
        xc0[rt] = *(const fx4*)src;
        xc1[rt] = *(const fx4*)(src + 4);
    }

    #pragma unroll 1
    for (int cc = 0; cc < 8; ++cc) {
        int kc = q * 8 + cc;
        fx4 xn0[4], xn1[4];
        if (cc < 7) {
            #pragma unroll
            for (int rt = 0; rt < 4; ++rt) {
                const float* src = A0 + (size_t)(c0 + rt * 16) * NV + (cc + 1) * 32;
                xn0[rt] = *(const fx4*)src;
                xn1[rt] = *(const fx4*)(src + 4);
            }
        }
        size_t bb = pvb + ((size_t)(kc * 4 + lg) * 64) * 8;
        s16x8 Bs0[4], Bs1[4], Bd0[4], Bd1[4];
        #pragma unroll
        for (int n = 0; n < 4; ++n) {
            size_t o = bb + (size_t)(n * 16 + lr) * 8;
            Bs0[n] = *(const s16x8*)(bsh + o);
            Bs1[n] = *(const s16x8*)(bsl + o);
            Bd0[n] = *(const s16x8*)(bdh + o);
            Bd1[n] = *(const s16x8*)(bdl + o);
        }
        s16x8 Aa[4], As[4];
        #pragma unroll
        for (int rt = 0; rt < 4; ++rt) {
            fx4 x0 = xc0[rt], x1 = xc1[rt];
            u32x4 aw, sw;
            aw[0] = packhi2(x0[0], x0[1]); aw[1] = packhi2(x0[2], x0[3]);
            aw[2] = packhi2(x1[0], x1[1]); aw[3] = packhi2(x1[2], x1[3]);
            sw[0] = aw[0] & 0x7FFF7FFFu; sw[1] = aw[1] & 0x7FFF7FFFu;
            sw[2] = aw[2] & 0x7FFF7FFFu; sw[3] = aw[3] & 0x7FFF7FFFu;
            Aa[rt] = __builtin_bit_cast(s16x8, aw);
            As[rt] = __builtin_bit_cast(s16x8, sw);
            unsigned int bits = 0;
            #pragma unroll
            for (int i = 0; i < 4; ++i) bits |= (((unsigned int)(int)x0[i]) & 3u) << (2 * i);
            #pragma unroll
            for (int i = 0; i < 4; ++i) bits |= (((unsigned int)(int)x1[i]) & 3u) << (8 + 2 * i);
            compb[(size_t)(kc * 4 + lg) * NC + (c0 + rt * 16 + lr)] = (unsigned short)bits;
        }
        #pragma unroll
        for (int rt = 0; rt < 4; ++rt)
            #pragma unroll
            for (int n = 0; n < 4; ++n) {
                acc[rt][n] = __builtin_amdgcn_mfma_f32_16x16x32_bf16(As[rt], Bs0[n], acc[rt][n], 0, 0, 0);
                acc[rt][n] = __builtin_amdgcn_mfma_f32_16x16x32_bf16(As[rt], Bs1[n], acc[rt][n], 0, 0, 0);
                acc[rt][n] = __builtin_amdgcn_mfma_f32_16x16x32_bf16(Aa[rt], Bd0[n], acc[rt][n], 0, 0, 0);
                acc[rt][n] = __builtin_amdgcn_mfma_f32_16x16x32_bf16(Aa[rt], Bd1[n], acc[rt][n], 0, 0, 0);
            }
        if (cc < 7) {
            #pragma unroll
            for (int rt = 0; rt < 4; ++rt) { xc0[rt] = xn0[rt]; xc1[rt] = xn1[rt]; }
        }
    }
    float* dst = cpart + (((size_t)q * NBATCH + b) * NC + c0) * DD;
    #pragma unroll
    for (int rt = 0; rt < 4; ++rt)
        #pragma unroll
        for (int n = 0; n < 4; ++n)
            #pragma unroll
            for (int r = 0; r < 4; ++r)
                dst[(size_t)(rt * 16 + lg * 4 + r) * DD + n * 16 + lr] = acc[rt][n][r];
}

// ---------------------------------------------------------------------------
// K2: c = relu(sum_q cpart + cb); emit (c@v0^T +/- c@v1^T)/2 hi/lo, tiled
// ---------------------------------------------------------------------------
__global__ __launch_bounds__(256) void k_projC(
    const float* __restrict__ cpart, const float* __restrict__ cb,
    const float* __restrict__ vblk,
    unsigned short* __restrict__ csh, unsigned short* __restrict__ csl,
    unsigned short* __restrict__ cdh, unsigned short* __restrict__ cdl)
{
    __shared__ float src[32][64];
    __shared__ float svb[2][64][65];
    int blk = blockIdx.x;
    int b = blk >> 8, kc = blk & 255;
    int t = threadIdx.x;
    const size_t qs = (size_t)NBATCH * NC * DD;
    const float* cs = cpart + ((size_t)b * NC + (size_t)kc * 32) * DD;
    for (int i = t; i < 2048; i += 256) {
        int k = i & 63;
        float v = cb[k];
        #pragma unroll
        for (int p = 0; p < 8; ++p) v += cs[i + p * qs];
        src[i >> 6][k] = fmaxf(v, 0.f);
    }
    for (int i = t; i < 8192; i += 256) {
        int pn = i >> 12, dout = (i >> 6) & 63, k = i & 63;
        svb[pn][k][dout] = vblk[i];
    }
    __syncthreads();
    int ks = t >> 6, dout = t & 63;
    float ap[8] = {0.f, 0.f, 0.f, 0.f, 0.f, 0.f, 0.f, 0.f};
    float an[8] = {0.f, 0.f, 0.f, 0.f, 0.f, 0.f, 0.f, 0.f};
    for (int k = 0; k < 64; ++k) {
        float w0 = svb[0][k][dout], w1 = svb[1][k][dout];
        #pragma unroll
        for (int c8 = 0; c8 < 8; ++c8) {
            float rc = src[ks * 8 + c8][k];
            ap[c8] += rc * w0;
            an[c8] += rc * w1;
        }
    }
    u16x8 vsh, vsl, vdh, vdl;
    #pragma unroll
    for (int c8 = 0; c8 < 8; ++c8) {
        float s = (ap[c8] + an[c8]) * 0.5f, dv = (ap[c8] - an[c8]) * 0.5f;
        unsigned short h = bf16_rne(s);
        vsh[c8] = h; vsl[c8] = bf16_rne(s - bf16_f32(h));
        h = bf16_rne(dv);
        vdh[c8] = h; vdl[c8] = bf16_rne(dv - bf16_f32(h));
    }
    size_t obase = (size_t)b * NC * DD + (((size_t)kc * 4 + ks) * 64 + dout) * 8;
    *(u16x8*)(csh + obase) = vsh;
    *(u16x8*)(csl + obase) = vsl;
    *(u16x8*)(cdh + obase) = vdh;
    *(u16x8*)(cdl + obase) = vdl;
}

// ---------------------------------------------------------------------------
// K3: npart[q][b][v][d] = |A|@(csh+csl) + A@(cdh+cdl), A decoded from comp.
// grid 2048 x 64, depth-1 comp-prefetch.
// ---------------------------------------------------------------------------
__global__ __launch_bounds__(64, 2) void k_phaseB(
    const unsigned short* __restrict__ comp,
    const unsigned short* __restrict__ csh, const unsigned short* __restrict__ csl,
    const unsigned short* __restrict__ cdh, const unsigned short* __restrict__ cdl,
    float* __restrict__ npart)
{
    int blk = blockIdx.x;
    int q = blk & 15;
    int rg = (blk >> 4) & 31;
    int b = blk >> 9;
    int l = threadIdx.x;
    int lr = l & 15, lg = l >> 4;
    int v0 = rg * 64;
    const unsigned short* compb = comp + (size_t)b * 256 * NC;
    const size_t cvb = (size_t)b * NC * DD;
    int sh_ = 2 * (lr & 7);
    fx4 acc[4][4];
    #pragma unroll
    for (int i = 0; i < 4; ++i)
        #pragma unroll
        for (int j = 0; j < 4; ++j) acc[i][j] = (fx4){0.f, 0.f, 0.f, 0.f};

    u16x8 uc[4];
    #pragma unroll
    for (int rt = 0; rt < 4; ++rt) {
        int v8 = (v0 + rt * 16 + lr) >> 3;
        uc[rt] = *(const u16x8*)(compb + (size_t)v8 * NC + (size_t)(q * 16) * 32 + lg * 8);
    }

    #pragma unroll 1
    for (int cc = 0; cc < 16; ++cc) {
        int kc = q * 16 + cc;
        int kb = kc * 32 + lg * 8;
        u16x8 un[4];
        if (cc < 15) {
            #pragma unroll
            for (int rt = 0; rt < 4; ++rt) {
                int v8 = (v0 + rt * 16 + lr) >> 3;
                un[rt] = *(const u16x8*)(compb + (size_t)v8 * NC + kb + 32);
            }
        }
        size_t bb = cvb + ((size_t)(kc * 4 + lg) * 64) * 8;
        s16x8 Bs0[4], Bs1[4], Bd0[4], Bd1[4];
        #pragma unroll
        for (int n = 0; n < 4; ++n) {
            size_t o = bb + (size_t)(n * 16 + lr) * 8;
            Bs0[n] = *(const s16x8*)(csh + o);
            Bs1[n] = *(const s16x8*)(csl + o);
            Bd0[n] = *(const s16x8*)(cdh + o);
            Bd1[n] = *(const s16x8*)(cdl + o);
        }
        s16x8 As[4], Aa[4];
        #pragma unroll
        for (int rt = 0; rt < 4; ++rt) {
            #pragma unroll
            for (int i = 0; i < 8; ++i) {
                unsigned int tb = ((unsigned int)uc[rt][i] >> sh_) & 3u;
                unsigned short m = (tb & 1u) ? (unsigned short)0x3F80 : (unsigned short)0;
                As[rt][i] = (short)m;
                Aa[rt][i] = (short)(m | ((tb & 2u) << 14));
            }
        }
        #pragma unroll
        for (int rt = 0; rt < 4; ++rt)
            #pragma unroll
            for (int n = 0; n < 4; ++n) {
                acc[rt][n] = __builtin_amdgcn_mfma_f32_16x16x32_bf16(As[rt], Bs0[n], acc[rt][n], 0, 0, 0);
                acc[rt][n] = __builtin_amdgcn_mfma_f32_16x16x32_bf16(As[rt], Bs1[n], acc[rt][n], 0, 0, 0);
                acc[rt][n] = __builtin_amdgcn_mfma_f32_16x16x32_bf16(Aa[rt], Bd0[n], acc[rt][n], 0, 0, 0);
                acc[rt][n] = __builtin_amdgcn_mfma_f32_16x16x32_bf16(Aa[rt], Bd1[n], acc[rt][n], 0, 0, 0);
            }
        if (cc < 15) {
            #pragma unroll
            for (int rt = 0; rt < 4; ++rt) uc[rt] = un[rt];
        }
    }
    float* dst = npart + (((size_t)q * NBATCH + b) * NV + v0) * DD;
    #pragma unroll
    for (int rt = 0; rt < 4; ++rt)
        #pragma unroll
        for (int n = 0; n < 4; ++n)
            #pragma unroll
            for (int r = 0; r < 4; ++r)
                dst[(size_t)(rt * 16 + lg * 4 + r) * DD + n * 16 + lr] = acc[rt][n][r];
}

// ---------------------------------------------------------------------------
// K4: v_emb=relu(sum_q npart+vb); av=tanh([g|v_emb]@Wg^T+bg); GRU -> out (f32)
// ---------------------------------------------------------------------------
__global__ __launch_bounds__(512) void k_gru(
    const float* __restrict__ npart, const float* __restrict__ vars,
    const float* __restrict__ gv, const float* __restrict__ vb,
    const float* __restrict__ Wg, const float* __restrict__ bg,
    const float* __restrict__ Wz, const float* __restrict__ Uz, const float* __restrict__ bz,
    const float* __restrict__ Wr, const float* __restrict__ Ur, const float* __restrict__ brr,
    const float* __restrict__ Wh, const float* __restrict__ Uh, const float* __restrict__ bh,
    float* __restrict__ out)
{
    __shared__ float sWg[72][65];
    __shared__ float sWz[64][65], sUz[64][65];
    __shared__ float sWr[64][65], sUr[64][65];
    __shared__ float sWh[64][65], sUh[64][65];
    __shared__ float scat[8][72];
    __shared__ float sprev[8][64];
    __shared__ float sav[8][64];
    __shared__ float srp[8][64];
    int t = threadIdx.x;
    for (int i = t * 4; i < 4608; i += 2048) {
        fx4 g4 = *(const fx4*)(Wg + i);
        int dout = i / 72, j = i - dout * 72;
        #pragma unroll
        for (int jj = 0; jj < 4; ++jj) sWg[j + jj][dout] = g4[jj];
    }
    for (int i = t * 4; i < 4096; i += 2048) {
        int dout = i >> 6, k = i & 63;
        fx4 a;
        a = *(const fx4*)(Wz + i);
        #pragma unroll
        for (int jj = 0; jj < 4; ++jj) sWz[k + jj][dout] = a[jj];
        a = *(const fx4*)(Uz + i);
        #pragma unroll
        for (int jj = 0; jj < 4; ++jj) sUz[k + jj][dout] = a[jj];
        a = *(const fx4*)(Wr + i);
        #pragma unroll
        for (int jj = 0; jj < 4; ++jj) sWr[k + jj][dout] = a[jj];
        a = *(const fx4*)(Ur + i);
        #pragma unroll
        for (int jj = 0; jj < 4; ++jj) sUr[k + jj][dout] = a[jj];
        a = *(const fx4*)(Wh + i);
        #pragma unroll
        for (int jj = 0; jj < 4; ++jj) sWh[k + jj][dout] = a[jj];
        a = *(const fx4*)(Uh + i);
        #pragma unroll
        for (int jj = 0; jj < 4; ++jj) sUh[k + jj][dout] = a[jj];
    }
    int rr = t >> 6, dout = t & 63;
    size_t row = (size_t)blockIdx.x * 8 + rr;
    float prev = vars[row * 64 + dout];
    float ve = vb[dout];
    const size_t qs = (size_t)NBATCH * NV * DD;
    #pragma unroll
    for (int s = 0; s < 16; ++s) ve += npart[(size_t)s * qs + row * 64 + dout];
    ve = fmaxf(ve, 0.f);
    scat[rr][8 + dout] = ve;
    if (dout < 8) scat[rr][dout] = gv[row * 8 + dout];
    sprev[rr][dout] = prev;
    __syncthreads();
    float a = bg[dout];
    for (int j = 0; j < 72; ++j) a += scat[rr][j] * sWg[j][dout];
    float av = 1.f - 2.f / (__expf(2.f * a) + 1.f);
    sav[rr][dout] = av;
    __syncthreads();
    float zi = bz[dout], ri = brr[dout], hwa = 0.f;
    for (int k = 0; k < 64; ++k) {
        float ak = sav[rr][k], pk = sprev[rr][k];
        zi += ak * sWz[k][dout] + pk * sUz[k][dout];
        ri += ak * sWr[k][dout] + pk * sUr[k][dout];
        hwa += ak * sWh[k][dout];
    }
    float z = 1.f / (1.f + __expf(-zi));
    float rgate = 1.f / (1.f + __expf(-ri));
    srp[rr][dout] = rgate * prev;
    __syncthreads();
    float hin = bh[dout] + hwa;
    for (int k = 0; k < 64; ++k) hin += srp[rr][k] * sUh[k][dout];
    float ht = 1.f - 2.f / (__expf(2.f * hin) + 1.f);
    out[row * 64 + dout] = (1.f - z) * prev + z * ht;
}

// ---------------------------------------------------------------------------
extern "C" void kernel_launch(void* const* d_in, const int* in_sizes, int n_in,
                              void* d_out, int out_size, void* d_ws, size_t ws_size,
                              hipStream_t stream) {
    (void)in_sizes; (void)n_in; (void)out_size; (void)ws_size;
    const float* vars = (const float*)d_in[0];
    const float* gv   = (const float*)d_in[1];
    const float* cmat = (const float*)d_in[2];
    const float* cblk = (const float*)d_in[4];
    const float* vblk = (const float*)d_in[5];
    const float* vb   = (const float*)d_in[6];
    const float* cb   = (const float*)d_in[7];
    const float* Wg   = (const float*)d_in[8];
    const float* bg   = (const float*)d_in[9];
    const float* Wz   = (const float*)d_in[10];
    const float* Uz   = (const float*)d_in[11];
    const float* bz   = (const float*)d_in[12];
    const float* Wr   = (const float*)d_in[13];
    const float* Ur   = (const float*)d_in[14];
    const float* br_  = (const float*)d_in[15];
    const float* Wh   = (const float*)d_in[16];
    const float* Uh   = (const float*)d_in[17];
    const float* bh   = (const float*)d_in[18];
    float* out = (float*)d_out;

    char* w = (char*)d_ws;
    const size_t MB = 1024 * 1024;
    unsigned short* bsh = (unsigned short*)(w + 0 * MB);
    unsigned short* bsl = (unsigned short*)(w + 1 * MB);
    unsigned short* bdh = (unsigned short*)(w + 2 * MB);
    unsigned short* bdl = (unsigned short*)(w + 3 * MB);
    unsigned short* csh = (unsigned short*)(w + 4 * MB);
    unsigned short* csl = (unsigned short*)(w + 8 * MB);
    unsigned short* cdh = (unsigned short*)(w + 12 * MB);
    unsigned short* cdl = (unsigned short*)(w + 16 * MB);
    float* cpart         = (float*)(w + 20 * MB);           // 64 MB [8][B][NC][DD]
    float* npart         = (float*)(w + 84 * MB);           // 32 MB [16][B][NV][DD]
    unsigned short* comp = (unsigned short*)(w + 116 * MB); // 16 MB [B][256][NC]

    k_prep_pv<<<256, 256, 0, stream>>>(vars, cblk, bsh, bsl, bdh, bdl);
    k_phaseA<<<4096, 64, 0, stream>>>(cmat, bsh, bsl, bdh, bdl, cpart, comp);
    k_projC<<<1024, 256, 0, stream>>>(cpart, cb, vblk, csh, csl, cdh, cdl);
    k_phaseB<<<2048, 64, 0, stream>>>(comp, csh, csl, cdh, cdl, npart);
    k_gru<<<1024, 512, 0, stream>>>(npart, vars, gv, vb, Wg, bg,
                                    Wz, Uz, bz, Wr, Ur, br_, Wh, Uh, bh, out);
}

// Round 4
// 170.228 us; speedup vs baseline: 1.6187x; 1.1578x over previous
//
#include <hip/hip_runtime.h>
#include <hip/hip_bf16.h>
#include <stdint.h>

#define NBATCH 4
#define NV 2048
#define NC 8192
#define DD 64

typedef __attribute__((ext_vector_type(8))) short s16x8;
typedef __attribute__((ext_vector_type(4))) float fx4;
typedef __attribute__((ext_vector_type(8))) unsigned short u16x8;
typedef __attribute__((ext_vector_type(4))) unsigned int u32x4;

static __device__ __forceinline__ unsigned short bf16_rne(float x) {
    union { float f; unsigned int u; } v; v.f = x;
    unsigned int u = v.u;
    u += 0x7FFFu + ((u >> 16) & 1u);
    return (unsigned short)(u >> 16);
}
static __device__ __forceinline__ float bf16_f32(unsigned short h) {
    union { unsigned int u; float f; } v; v.u = ((unsigned int)h) << 16;
    return v.f;
}
// pack high16(a) into low half, high16(b) into high half (exact for {0,±1})
static __device__ __forceinline__ unsigned int packhi2(float a, float b) {
    return __builtin_amdgcn_perm(__builtin_bit_cast(unsigned int, b),
                                 __builtin_bit_cast(unsigned int, a), 0x07060302u);
}

// ---------------------------------------------------------------------------
// K0: s=(pos+neg)/2, d=(pos-neg)/2 of variables @ c_block[pn]^T, hi/lo bf16,
// tiled B-frag layout idx(v,dout) = ((v/8)*64 + dout)*8 + (v%8)  (per batch)
// ---------------------------------------------------------------------------
__global__ __launch_bounds__(256) void k_prep_pv(
    const float* __restrict__ vars, const float* __restrict__ cblk,
    unsigned short* __restrict__ bsh, unsigned short* __restrict__ bsl,
    unsigned short* __restrict__ bdh, unsigned short* __restrict__ bdl)
{
    __shared__ float sv[32][64];
    __shared__ float scb[2][64][65];
    int blk = blockIdx.x;
    int b = blk >> 6, ch = blk & 63;
    int t = threadIdx.x;
    const float* vsrc = vars + ((size_t)b * NV + (size_t)ch * 32) * DD;
    for (int i = t; i < 32 * 64; i += 256) sv[i >> 6][i & 63] = vsrc[i];
    for (int i = t; i < 2 * 64 * 64; i += 256) {
        int pn = i >> 12, dout = (i >> 6) & 63, k = i & 63;
        scb[pn][k][dout] = cblk[i];
    }
    __syncthreads();
    int ks = t >> 6, dout = t & 63;
    u16x8 vsh, vsl, vdh, vdl;
    #pragma unroll
    for (int c8 = 0; c8 < 8; ++c8) {
        int vloc = ks * 8 + c8;
        float ap = 0.f, an = 0.f;
        for (int k = 0; k < 64; ++k) {
            float vv = sv[vloc][k];
            ap += vv * scb[0][k][dout];
            an += vv * scb[1][k][dout];
        }
        float s = (ap + an) * 0.5f, dv = (ap - an) * 0.5f;
        unsigned short h = bf16_rne(s);
        vsh[c8] = h; vsl[c8] = bf16_rne(s - bf16_f32(h));
        h = bf16_rne(dv);
        vdh[c8] = h; vdl[c8] = bf16_rne(dv - bf16_f32(h));
    }
    size_t obase = (size_t)b * NV * DD + (((size_t)ch * 4 + ks) * 64 + dout) * 8;
    *(u16x8*)(bsh + obase) = vsh;
    *(u16x8*)(bsl + obase) = vsl;
    *(u16x8*)(bdh + obase) = vdh;
    *(u16x8*)(bdl + obase) = vdl;
}

// ---------------------------------------------------------------------------
// K1: cpart[q][b][c][d] = |A|@(bsh+bsl) + A@(bdh+bdl) over K-quarter q.
// 256-row 4-wave blocks, B-frags LDS-staged (double buffered, reg-staged,
// one barrier per chunk). Emits comp 2-bit codes. grid 512 x 256.
// ---------------------------------------------------------------------------
__global__ __launch_bounds__(256, 2) void k_phaseA(
    const float* __restrict__ cmat,
    const unsigned short* __restrict__ bsh, const unsigned short* __restrict__ bsl,
    const unsigned short* __restrict__ bdh, const unsigned short* __restrict__ bdl,
    float* __restrict__ cpart, unsigned short* __restrict__ comp)
{
    __shared__ short lds[2][4][2048];   // [buf][array][chunk shorts] = 32 KB
    int blk = blockIdx.x;
    int q = blk & 3;
    int rg = (blk >> 2) & 31;
    int b = blk >> 7;
    int t = threadIdx.x;
    int wv = t >> 6;
    int l = t & 63;
    int lr = l & 15, lg = l >> 4;
    int c0 = rg * 256 + wv * 64;
    const float* A0 = cmat + (size_t)b * NC * NV + (size_t)lr * NV + q * 512 + lg * 8;
    const size_t pvb = (size_t)b * NV * DD;
    unsigned short* compb = comp + (size_t)b * 256 * NC;

    fx4 acc[4][4];
    #pragma unroll
    for (int i = 0; i < 4; ++i)
        #pragma unroll
        for (int j = 0; j < 4; ++j) acc[i][j] = (fx4){0.f, 0.f, 0.f, 0.f};

    // prologue: stage chunk 0 + load A regs chunk 0
    {
        size_t so = pvb + (size_t)(q * 16) * 2048 + (size_t)t * 8;
        s16x8 sA = *(const s16x8*)(bsh + so);
        s16x8 sB = *(const s16x8*)(bsl + so);
        s16x8 sC = *(const s16x8*)(bdh + so);
        s16x8 sD = *(const s16x8*)(bdl + so);
        *(s16x8*)&lds[0][0][t * 8] = sA;
        *(s16x8*)&lds[0][1][t * 8] = sB;
        *(s16x8*)&lds[0][2][t * 8] = sC;
        *(s16x8*)&lds[0][3][t * 8] = sD;
    }
    fx4 xc0[4], xc1[4];
    #pragma unroll
    for (int rt = 0; rt < 4; ++rt) {
        const float* src = A0 + (size_t)(c0 + rt * 16) * NV;
        xc0[rt] = *(const fx4*)src;
        xc1[rt] = *(const fx4*)(src + 4);
    }
    __syncthreads();

    int cur = 0;
    #pragma unroll 1
    for (int cc = 0; cc < 16; ++cc) {
        int kc = q * 16 + cc;
        // prefetch next A rows + next B-stage (regs) — consumed after compute
        fx4 xn0[4], xn1[4];
        s16x8 sA, sB, sC, sD;
        if (cc < 15) {
            #pragma unroll
            for (int rt = 0; rt < 4; ++rt) {
                const float* src = A0 + (size_t)(c0 + rt * 16) * NV + (cc + 1) * 32;
                xn0[rt] = *(const fx4*)src;
                xn1[rt] = *(const fx4*)(src + 4);
            }
            size_t so = pvb + (size_t)(kc + 1) * 2048 + (size_t)t * 8;
            sA = *(const s16x8*)(bsh + so);
            sB = *(const s16x8*)(bsl + so);
            sC = *(const s16x8*)(bdh + so);
            sD = *(const s16x8*)(bdl + so);
        }
        // decode current A + comp codes
        s16x8 Aa[4], As[4];
        #pragma unroll
        for (int rt = 0; rt < 4; ++rt) {
            fx4 x0 = xc0[rt], x1 = xc1[rt];
            u32x4 aw, sw;
            aw[0] = packhi2(x0[0], x0[1]); aw[1] = packhi2(x0[2], x0[3]);
            aw[2] = packhi2(x1[0], x1[1]); aw[3] = packhi2(x1[2], x1[3]);
            sw[0] = aw[0] & 0x7FFF7FFFu; sw[1] = aw[1] & 0x7FFF7FFFu;
            sw[2] = aw[2] & 0x7FFF7FFFu; sw[3] = aw[3] & 0x7FFF7FFFu;
            Aa[rt] = __builtin_bit_cast(s16x8, aw);
            As[rt] = __builtin_bit_cast(s16x8, sw);
            unsigned int bits = 0;
            #pragma unroll
            for (int i = 0; i < 4; ++i) bits |= (((unsigned int)(int)x0[i]) & 3u) << (2 * i);
            #pragma unroll
            for (int i = 0; i < 4; ++i) bits |= (((unsigned int)(int)x1[i]) & 3u) << (8 + 2 * i);
            compb[(size_t)(kc * 4 + lg) * NC + (c0 + rt * 16 + lr)] = (unsigned short)bits;
        }
        // MFMA from LDS (4 B-frags live at a time)
        const short* bufp = &lds[cur][0][0];
        #pragma unroll
        for (int n = 0; n < 4; ++n) {
            int off = lg * 512 + (n * 16 + lr) * 8;
            s16x8 Bs0 = *(const s16x8*)(bufp + off);
            s16x8 Bs1 = *(const s16x8*)(bufp + 2048 + off);
            s16x8 Bd0 = *(const s16x8*)(bufp + 4096 + off);
            s16x8 Bd1 = *(const s16x8*)(bufp + 6144 + off);
            #pragma unroll
            for (int rt = 0; rt < 4; ++rt) {
                acc[rt][n] = __builtin_amdgcn_mfma_f32_16x16x32_bf16(As[rt], Bs0, acc[rt][n], 0, 0, 0);
                acc[rt][n] = __builtin_amdgcn_mfma_f32_16x16x32_bf16(As[rt], Bs1, acc[rt][n], 0, 0, 0);
                acc[rt][n] = __builtin_amdgcn_mfma_f32_16x16x32_bf16(Aa[rt], Bd0, acc[rt][n], 0, 0, 0);
                acc[rt][n] = __builtin_amdgcn_mfma_f32_16x16x32_bf16(Aa[rt], Bd1, acc[rt][n], 0, 0, 0);
            }
        }
        // write next stage to the other buffer
        if (cc < 15) {
            short* np = &lds[cur ^ 1][0][0];
            *(s16x8*)(np + t * 8) = sA;
            *(s16x8*)(np + 2048 + t * 8) = sB;
            *(s16x8*)(np + 4096 + t * 8) = sC;
            *(s16x8*)(np + 6144 + t * 8) = sD;
            #pragma unroll
            for (int rt = 0; rt < 4; ++rt) { xc0[rt] = xn0[rt]; xc1[rt] = xn1[rt]; }
        }
        __syncthreads();
        cur ^= 1;
    }
    float* dst = cpart + (((size_t)q * NBATCH + b) * NC + c0) * DD;
    #pragma unroll
    for (int rt = 0; rt < 4; ++rt)
        #pragma unroll
        for (int n = 0; n < 4; ++n)
            #pragma unroll
            for (int r = 0; r < 4; ++r)
                dst[(size_t)(rt * 16 + lg * 4 + r) * DD + n * 16 + lr] = acc[rt][n][r];
}

// ---------------------------------------------------------------------------
// K2: c = relu(sum_q cpart + cb); emit (c@v0^T +/- c@v1^T)/2 hi/lo, tiled
// ---------------------------------------------------------------------------
__global__ __launch_bounds__(256) void k_projC(
    const float* __restrict__ cpart, const float* __restrict__ cb,
    const float* __restrict__ vblk,
    unsigned short* __restrict__ csh, unsigned short* __restrict__ csl,
    unsigned short* __restrict__ cdh, unsigned short* __restrict__ cdl)
{
    __shared__ float src[32][64];
    __shared__ float svb[2][64][65];
    int blk = blockIdx.x;
    int b = blk >> 8, kc = blk & 255;
    int t = threadIdx.x;
    const size_t qs = (size_t)NBATCH * NC * DD;
    const float* cs = cpart + ((size_t)b * NC + (size_t)kc * 32) * DD;
    for (int i = t; i < 2048; i += 256) {
        int k = i & 63;
        float v = cb[k];
        #pragma unroll
        for (int p = 0; p < 4; ++p) v += cs[i + p * qs];
        src[i >> 6][k] = fmaxf(v, 0.f);
    }
    for (int i = t; i < 8192; i += 256) {
        int pn = i >> 12, dout = (i >> 6) & 63, k = i & 63;
        svb[pn][k][dout] = vblk[i];
    }
    __syncthreads();
    int ks = t >> 6, dout = t & 63;
    float ap[8] = {0.f, 0.f, 0.f, 0.f, 0.f, 0.f, 0.f, 0.f};
    float an[8] = {0.f, 0.f, 0.f, 0.f, 0.f, 0.f, 0.f, 0.f};
    for (int k = 0; k < 64; ++k) {
        float w0 = svb[0][k][dout], w1 = svb[1][k][dout];
        #pragma unroll
        for (int c8 = 0; c8 < 8; ++c8) {
            float rc = src[ks * 8 + c8][k];
            ap[c8] += rc * w0;
            an[c8] += rc * w1;
        }
    }
    u16x8 vsh, vsl, vdh, vdl;
    #pragma unroll
    for (int c8 = 0; c8 < 8; ++c8) {
        float s = (ap[c8] + an[c8]) * 0.5f, dv = (ap[c8] - an[c8]) * 0.5f;
        unsigned short h = bf16_rne(s);
        vsh[c8] = h; vsl[c8] = bf16_rne(s - bf16_f32(h));
        h = bf16_rne(dv);
        vdh[c8] = h; vdl[c8] = bf16_rne(dv - bf16_f32(h));
    }
    size_t obase = (size_t)b * NC * DD + (((size_t)kc * 4 + ks) * 64 + dout) * 8;
    *(u16x8*)(csh + obase) = vsh;
    *(u16x8*)(csl + obase) = vsl;
    *(u16x8*)(cdh + obase) = vdh;
    *(u16x8*)(cdl + obase) = vdl;
}

// ---------------------------------------------------------------------------
// K3: npart[q][b][v][d] = |A|@(csh+csl) + A@(cdh+cdl), A decoded from comp.
// 256-row 4-wave blocks, B-frags LDS-staged. grid 512 x 256.
// ---------------------------------------------------------------------------
__global__ __launch_bounds__(256, 2) void k_phaseB(
    const unsigned short* __restrict__ comp,
    const unsigned short* __restrict__ csh, const unsigned short* __restrict__ csl,
    const unsigned short* __restrict__ cdh, const unsigned short* __restrict__ cdl,
    float* __restrict__ npart)
{
    __shared__ short lds[2][4][2048];
    int blk = blockIdx.x;
    int q = blk & 15;
    int rg = (blk >> 4) & 7;
    int b = blk >> 7;
    int t = threadIdx.x;
    int wv = t >> 6;
    int l = t & 63;
    int lr = l & 15, lg = l >> 4;
    int v0 = rg * 256 + wv * 64;
    const unsigned short* compb = comp + (size_t)b * 256 * NC;
    const size_t cvb = (size_t)b * NC * DD;
    int sh_ = 2 * (lr & 7);
    const unsigned short* cp0 = compb + (size_t)((v0 + 0 * 16 + lr) >> 3) * NC + lg * 8;
    const unsigned short* cp1 = compb + (size_t)((v0 + 1 * 16 + lr) >> 3) * NC + lg * 8;
    const unsigned short* cp2 = compb + (size_t)((v0 + 2 * 16 + lr) >> 3) * NC + lg * 8;
    const unsigned short* cp3 = compb + (size_t)((v0 + 3 * 16 + lr) >> 3) * NC + lg * 8;

    fx4 acc[4][4];
    #pragma unroll
    for (int i = 0; i < 4; ++i)
        #pragma unroll
        for (int j = 0; j < 4; ++j) acc[i][j] = (fx4){0.f, 0.f, 0.f, 0.f};

    // prologue: stage chunk 0, load comp chunk 0
    {
        size_t so = cvb + (size_t)(q * 16) * 2048 + (size_t)t * 8;
        s16x8 sA = *(const s16x8*)(csh + so);
        s16x8 sB = *(const s16x8*)(csl + so);
        s16x8 sC = *(const s16x8*)(cdh + so);
        s16x8 sD = *(const s16x8*)(cdl + so);
        *(s16x8*)&lds[0][0][t * 8] = sA;
        *(s16x8*)&lds[0][1][t * 8] = sB;
        *(s16x8*)&lds[0][2][t * 8] = sC;
        *(s16x8*)&lds[0][3][t * 8] = sD;
    }
    u16x8 uc0, uc1, uc2, uc3;
    {
        int kb = (q * 16) * 32;
        uc0 = *(const u16x8*)(cp0 + kb);
        uc1 = *(const u16x8*)(cp1 + kb);
        uc2 = *(const u16x8*)(cp2 + kb);
        uc3 = *(const u16x8*)(cp3 + kb);
    }
    __syncthreads();

    int cur = 0;
    #pragma unroll 1
    for (int cc = 0; cc < 16; ++cc) {
        int kc = q * 16 + cc;
        u16x8 un0, un1, un2, un3;
        s16x8 sA, sB, sC, sD;
        if (cc < 15) {
            int kb = (kc + 1) * 32;
            un0 = *(const u16x8*)(cp0 + kb);
            un1 = *(const u16x8*)(cp1 + kb);
            un2 = *(const u16x8*)(cp2 + kb);
            un3 = *(const u16x8*)(cp3 + kb);
            size_t so = cvb + (size_t)(kc + 1) * 2048 + (size_t)t * 8;
            sA = *(const s16x8*)(csh + so);
            sB = *(const s16x8*)(csl + so);
            sC = *(const s16x8*)(cdh + so);
            sD = *(const s16x8*)(cdl + so);
        }
        // decode A from 2-bit codes
        s16x8 As[4], Aa[4];
        u16x8 ucs[4] = {uc0, uc1, uc2, uc3};
        #pragma unroll
        for (int rt = 0; rt < 4; ++rt) {
            #pragma unroll
            for (int i = 0; i < 8; ++i) {
                unsigned int tb = ((unsigned int)ucs[rt][i] >> sh_) & 3u;
                unsigned short m = (tb & 1u) ? (unsigned short)0x3F80 : (unsigned short)0;
                As[rt][i] = (short)m;
                Aa[rt][i] = (short)(m | ((tb & 2u) << 14));
            }
        }
        const short* bufp = &lds[cur][0][0];
        #pragma unroll
        for (int n = 0; n < 4; ++n) {
            int off = lg * 512 + (n * 16 + lr) * 8;
            s16x8 Bs0 = *(const s16x8*)(bufp + off);
            s16x8 Bs1 = *(const s16x8*)(bufp + 2048 + off);
            s16x8 Bd0 = *(const s16x8*)(bufp + 4096 + off);
            s16x8 Bd1 = *(const s16x8*)(bufp + 6144 + off);
            #pragma unroll
            for (int rt = 0; rt < 4; ++rt) {
                acc[rt][n] = __builtin_amdgcn_mfma_f32_16x16x32_bf16(As[rt], Bs0, acc[rt][n], 0, 0, 0);
                acc[rt][n] = __builtin_amdgcn_mfma_f32_16x16x32_bf16(As[rt], Bs1, acc[rt][n], 0, 0, 0);
                acc[rt][n] = __builtin_amdgcn_mfma_f32_16x16x32_bf16(Aa[rt], Bd0, acc[rt][n], 0, 0, 0);
                acc[rt][n] = __builtin_amdgcn_mfma_f32_16x16x32_bf16(Aa[rt], Bd1, acc[rt][n], 0, 0, 0);
            }
        }
        if (cc < 15) {
            short* np = &lds[cur ^ 1][0][0];
            *(s16x8*)(np + t * 8) = sA;
            *(s16x8*)(np + 2048 + t * 8) = sB;
            *(s16x8*)(np + 4096 + t * 8) = sC;
            *(s16x8*)(np + 6144 + t * 8) = sD;
            uc0 = un0; uc1 = un1; uc2 = un2; uc3 = un3;
        }
        __syncthreads();
        cur ^= 1;
    }
    float* dst = npart + (((size_t)q * NBATCH + b) * NV + v0) * DD;
    #pragma unroll
    for (int rt = 0; rt < 4; ++rt)
        #pragma unroll
        for (int n = 0; n < 4; ++n)
            #pragma unroll
            for (int r = 0; r < 4; ++r)
                dst[(size_t)(rt * 16 + lg * 4 + r) * DD + n * 16 + lr] = acc[rt][n][r];
}

// ---------------------------------------------------------------------------
// K4: v_emb=relu(sum_q npart+vb); av=tanh([g|v_emb]@Wg^T+bg); GRU -> out (f32)
// grid 256 x 512, 4 row-iterations per block (weights staged once).
// ---------------------------------------------------------------------------
__global__ __launch_bounds__(512) void k_gru(
    const float* __restrict__ npart, const float* __restrict__ vars,
    const float* __restrict__ gv, const float* __restrict__ vb,
    const float* __restrict__ Wg, const float* __restrict__ bg,
    const float* __restrict__ Wz, const float* __restrict__ Uz, const float* __restrict__ bz,
    const float* __restrict__ Wr, const float* __restrict__ Ur, const float* __restrict__ brr,
    const float* __restrict__ Wh, const float* __restrict__ Uh, const float* __restrict__ bh,
    float* __restrict__ out)
{
    __shared__ float sWg[72][65];
    __shared__ float sWz[64][65], sUz[64][65];
    __shared__ float sWr[64][65], sUr[64][65];
    __shared__ float sWh[64][65], sUh[64][65];
    __shared__ float scat[8][72];
    __shared__ float sprev[8][64];
    __shared__ float sav[8][64];
    __shared__ float srp[8][64];
    int t = threadIdx.x;
    for (int i = t * 4; i < 4608; i += 2048) {
        fx4 g4 = *(const fx4*)(Wg + i);
        int dout = i / 72, j = i - dout * 72;
        #pragma unroll
        for (int jj = 0; jj < 4; ++jj) sWg[j + jj][dout] = g4[jj];
    }
    for (int i = t * 4; i < 4096; i += 2048) {
        int dout = i >> 6, k = i & 63;
        fx4 a;
        a = *(const fx4*)(Wz + i);
        #pragma unroll
        for (int jj = 0; jj < 4; ++jj) sWz[k + jj][dout] = a[jj];
        a = *(const fx4*)(Uz + i);
        #pragma unroll
        for (int jj = 0; jj < 4; ++jj) sUz[k + jj][dout] = a[jj];
        a = *(const fx4*)(Wr + i);
        #pragma unroll
        for (int jj = 0; jj < 4; ++jj) sWr[k + jj][dout] = a[jj];
        a = *(const fx4*)(Ur + i);
        #pragma unroll
        for (int jj = 0; jj < 4; ++jj) sUr[k + jj][dout] = a[jj];
        a = *(const fx4*)(Wh + i);
        #pragma unroll
        for (int jj = 0; jj < 4; ++jj) sWh[k + jj][dout] = a[jj];
        a = *(const fx4*)(Uh + i);
        #pragma unroll
        for (int jj = 0; jj < 4; ++jj) sUh[k + jj][dout] = a[jj];
    }
    int rr = t >> 6, dout = t & 63;
    const size_t qs = (size_t)NBATCH * NV * DD;
    #pragma unroll 1
    for (int it = 0; it < 4; ++it) {
        size_t row = (size_t)blockIdx.x * 32 + it * 8 + rr;
        float prev = vars[row * 64 + dout];
        float ve = vb[dout];
        #pragma unroll
        for (int s = 0; s < 16; ++s) ve += npart[(size_t)s * qs + row * 64 + dout];
        ve = fmaxf(ve, 0.f);
        scat[rr][8 + dout] = ve;
        if (dout < 8) scat[rr][dout] = gv[row * 8 + dout];
        sprev[rr][dout] = prev;
        __syncthreads();
        float a = bg[dout];
        for (int j = 0; j < 72; ++j) a += scat[rr][j] * sWg[j][dout];
        float av = 1.f - 2.f / (__expf(2.f * a) + 1.f);
        sav[rr][dout] = av;
        __syncthreads();
        float zi = bz[dout], ri = brr[dout], hwa = 0.f;
        for (int k = 0; k < 64; ++k) {
            float ak = sav[rr][k], pk = sprev[rr][k];
            zi += ak * sWz[k][dout] + pk * sUz[k][dout];
            ri += ak * sWr[k][dout] + pk * sUr[k][dout];
            hwa += ak * sWh[k][dout];
        }
        float z = 1.f / (1.f + __expf(-zi));
        float rgate = 1.f / (1.f + __expf(-ri));
        srp[rr][dout] = rgate * prev;
        __syncthreads();
        float hin = bh[dout] + hwa;
        for (int k = 0; k < 64; ++k) hin += srp[rr][k] * sUh[k][dout];
        float ht = 1.f - 2.f / (__expf(2.f * hin) + 1.f);
        out[row * 64 + dout] = (1.f - z) * prev + z * ht;
        __syncthreads();
    }
}

// ---------------------------------------------------------------------------
extern "C" void kernel_launch(void* const* d_in, const int* in_sizes, int n_in,
                              void* d_out, int out_size, void* d_ws, size_t ws_size,
                              hipStream_t stream) {
    (void)in_sizes; (void)n_in; (void)out_size; (void)ws_size;
    const float* vars = (const float*)d_in[0];
    const float* gv   = (const float*)d_in[1];
    const float* cmat = (const float*)d_in[2];
    const float* cblk = (const float*)d_in[4];
    const float* vblk = (const float*)d_in[5];
    const float* vb   = (const float*)d_in[6];
    const float* cb   = (const float*)d_in[7];
    const float* Wg   = (const float*)d_in[8];
    const float* bg   = (const float*)d_in[9];
    const float* Wz   = (const float*)d_in[10];
    const float* Uz   = (const float*)d_in[11];
    const float* bz   = (const float*)d_in[12];
    const float* Wr   = (const float*)d_in[13];
    const float* Ur   = (const float*)d_in[14];
    const float* br_  = (const float*)d_in[15];
    const float* Wh   = (const float*)d_in[16];
    const float* Uh   = (const float*)d_in[17];
    const float* bh   = (const float*)d_in[18];
    float* out = (float*)d_out;

    char* w = (char*)d_ws;
    const size_t MB = 1024 * 1024;
    unsigned short* bsh = (unsigned short*)(w + 0 * MB);
    unsigned short* bsl = (unsigned short*)(w + 1 * MB);
    unsigned short* bdh = (unsigned short*)(w + 2 * MB);
    unsigned short* bdl = (unsigned short*)(w + 3 * MB);
    unsigned short* csh = (unsigned short*)(w + 4 * MB);
    unsigned short* csl = (unsigned short*)(w + 8 * MB);
    unsigned short* cdh = (unsigned short*)(w + 12 * MB);
    unsigned short* cdl = (unsigned short*)(w + 16 * MB);
    float* cpart         = (float*)(w + 20 * MB);           // 32 MB [4][B][NC][DD]
    float* npart         = (float*)(w + 52 * MB);           // 32 MB [16][B][NV][DD]
    unsigned short* comp = (unsigned short*)(w + 84 * MB);  // 16 MB [B][256][NC]

    k_prep_pv<<<256, 256, 0, stream>>>(vars, cblk, bsh, bsl, bdh, bdl);
    k_phaseA<<<512, 256, 0, stream>>>(cmat, bsh, bsl, bdh, bdl, cpart, comp);
    k_projC<<<1024, 256, 0, stream>>>(cpart, cb, vblk, csh, csl, cdh, cdl);
    k_phaseB<<<512, 256, 0, stream>>>(comp, csh, csl, cdh, cdl, npart);
    k_gru<<<256, 512, 0, stream>>>(npart, vars, gv, vb, Wg, bg,
                                   Wz, Uz, bz, Wr, Ur, br_, Wh, Uh, bh, out);
}

// Round 6
// 166.404 us; speedup vs baseline: 1.6559x; 1.0230x over previous
//
#include <hip/hip_runtime.h>
#include <hip/hip_bf16.h>
#include <stdint.h>

#define NBATCH 4
#define NV 2048
#define NC 8192
#define DD 64

typedef __attribute__((ext_vector_type(8))) short s16x8;
typedef __attribute__((ext_vector_type(4))) float fx4;
typedef __attribute__((ext_vector_type(8))) unsigned short u16x8;
typedef __attribute__((ext_vector_type(4))) int i32x4;
typedef __attribute__((ext_vector_type(2))) unsigned int u32x2;

static __device__ __forceinline__ unsigned short bf16_rne(float x) {
    union { float f; unsigned int u; } v; v.f = x;
    unsigned int u = v.u;
    u += 0x7FFFu + ((u >> 16) & 1u);
    return (unsigned short)(u >> 16);
}
static __device__ __forceinline__ float bf16_f32(unsigned short h) {
    union { unsigned int u; float f; } v; v.u = ((unsigned int)h) << 16;
    return v.f;
}
static __device__ __forceinline__ void gload_lds16(const void* g, void* l) {
    __builtin_amdgcn_global_load_lds(
        (const __attribute__((address_space(1))) unsigned int*)g,
        (__attribute__((address_space(3))) unsigned int*)l, 16, 0, 0);
}

// ---------------------------------------------------------------------------
// K0: s=(pos+neg)/2, d=(pos-neg)/2 of variables @ c_block[pn]^T, quantized to
// int16 (scale 2^12), split hi/lo i8, stored in i8 MFMA B-frag layout:
// off(b,v,dout) = ((b*32 + v/64)*64 + dout)*64 + ((v>>4)&3)*16 + (v&15)
// ---------------------------------------------------------------------------
__global__ __launch_bounds__(256) void k_prep_pv(
    const float* __restrict__ vars, const float* __restrict__ cblk,
    char* __restrict__ qsh, char* __restrict__ qsl,
    char* __restrict__ qdh, char* __restrict__ qdl)
{
    __shared__ float sv[32][64];
    __shared__ float scb[2][64][65];
    int blk = blockIdx.x;
    int b = blk >> 6, ch = blk & 63;
    int t = threadIdx.x;
    const float* vsrc = vars + ((size_t)b * NV + (size_t)ch * 32) * DD;
    for (int i = t; i < 32 * 64; i += 256) sv[i >> 6][i & 63] = vsrc[i];
    for (int i = t; i < 2 * 64 * 64; i += 256) {
        int pn = i >> 12, dout = (i >> 6) & 63, k = i & 63;
        scb[pn][k][dout] = cblk[i];
    }
    __syncthreads();
    int ks = t >> 6, dout = t & 63;
    unsigned int wsh[2] = {0, 0}, wsl[2] = {0, 0}, wdh[2] = {0, 0}, wdl[2] = {0, 0};
    #pragma unroll
    for (int c8 = 0; c8 < 8; ++c8) {
        int vloc = ks * 8 + c8;
        float ap = 0.f, an = 0.f;
        for (int k = 0; k < 64; ++k) {
            float vv = sv[vloc][k];
            ap += vv * scb[0][k][dout];
            an += vv * scb[1][k][dout];
        }
        float s = (ap + an) * 0.5f, dv = (ap - an) * 0.5f;
        int qs_ = (int)rintf(s * 4096.f);
        int qd_ = (int)rintf(dv * 4096.f);
        qs_ = min(max(qs_, -32511), 32511);
        qd_ = min(max(qd_, -32511), 32511);
        int sh = (qs_ + 128) >> 8, sl = qs_ - (sh << 8);
        int dh = (qd_ + 128) >> 8, dl = qd_ - (dh << 8);
        int w = c8 >> 2, sft = (c8 & 3) * 8;
        wsh[w] |= (unsigned int)(sh & 0xFF) << sft;
        wsl[w] |= (unsigned int)(sl & 0xFF) << sft;
        wdh[w] |= (unsigned int)(dh & 0xFF) << sft;
        wdl[w] |= (unsigned int)(dl & 0xFF) << sft;
    }
    int kc = ch >> 1;
    int lg = ((ch & 1) << 1) | (ks >> 1);
    size_t off = (((size_t)(b * 32 + kc) * 64 + dout) * 4 + lg) * 16 + (ks & 1) * 8;
    *(u32x2*)(qsh + off) = (u32x2){wsh[0], wsh[1]};
    *(u32x2*)(qsl + off) = (u32x2){wsl[0], wsl[1]};
    *(u32x2*)(qdh + off) = (u32x2){wdh[0], wdh[1]};
    *(u32x2*)(qdl + off) = (u32x2){wdl[0], wdl[1]};
}

// ---------------------------------------------------------------------------
// K1: i8 fixed-point phase A. cpart[q][b][c][d] = (|A|@s + A@d) via
// mfma_i32_16x16x64_i8 with hi/lo i32 accumulators. 128-row 4-wave blocks,
// K-quarter q, B-planes via global_load_lds double-buffer. Emits comp codes.
// grid 1024 x 256. blk = rg*16 + (b*4+q)  (same-(b,q) -> same XCD).
// ---------------------------------------------------------------------------
__global__ __launch_bounds__(256, 2) void k_phaseA(
    const float* __restrict__ cmat,
    const char* __restrict__ qsh, const char* __restrict__ qsl,
    const char* __restrict__ qdh, const char* __restrict__ qdl,
    float* __restrict__ cpart, unsigned short* __restrict__ comp)
{
    __shared__ char lds[2][16384];
    int blk = blockIdx.x;
    int combo = blk & 15;
    int rg = blk >> 4;
    int b = combo >> 2;
    int q = combo & 3;
    int t = threadIdx.x;
    int wv = t >> 6, l = t & 63, lr = l & 15, lg = l >> 4;
    int c0 = rg * 128 + wv * 32;
    const float* A0 = cmat + (size_t)b * NC * NV + (size_t)lr * NV + q * 512 + lg * 16;
    unsigned short* compb = comp + (size_t)b * 256 * NC;

    i32x4 ahi[2][4], alo[2][4];
    #pragma unroll
    for (int i = 0; i < 2; ++i)
        #pragma unroll
        for (int j = 0; j < 4; ++j) { ahi[i][j] = (i32x4){0,0,0,0}; alo[i][j] = (i32x4){0,0,0,0}; }

    // prologue: stage chunk 0 + A regs chunk 0
    {
        size_t gb = ((size_t)(b * 32 + q * 8)) * 4096 + (size_t)t * 16;
        char* lp = &lds[0][t * 16];
        gload_lds16(qsh + gb, lp);
        gload_lds16(qsl + gb, lp + 4096);
        gload_lds16(qdh + gb, lp + 8192);
        gload_lds16(qdl + gb, lp + 12288);
    }
    fx4 xc[2][4], xn[2][4];
    #pragma unroll
    for (int rt = 0; rt < 2; ++rt)
        #pragma unroll
        for (int j4 = 0; j4 < 4; ++j4)
            xc[rt][j4] = *(const fx4*)(A0 + (size_t)(c0 + rt * 16) * NV + j4 * 4);
    __syncthreads();

    int cur = 0;
    #pragma unroll 1
    for (int cc = 0; cc < 8; ++cc) {
        if (cc < 7) {
            size_t gb = ((size_t)(b * 32 + q * 8 + cc + 1)) * 4096 + (size_t)t * 16;
            char* lp = &lds[cur ^ 1][t * 16];
            gload_lds16(qsh + gb, lp);
            gload_lds16(qsl + gb, lp + 4096);
            gload_lds16(qdh + gb, lp + 8192);
            gload_lds16(qdl + gb, lp + 12288);
            #pragma unroll
            for (int rt = 0; rt < 2; ++rt)
                #pragma unroll
                for (int j4 = 0; j4 < 4; ++j4)
                    xn[rt][j4] = *(const fx4*)(A0 + (size_t)(c0 + rt * 16) * NV + (cc + 1) * 64 + j4 * 4);
        }
        // decode A: sgn bytes {0,1,0xFF}, abs bytes {0,1}; comp 2-bit codes
        i32x4 Asgn[2], Aabs[2];
        #pragma unroll
        for (int rt = 0; rt < 2; ++rt) {
            int tt[16];
            #pragma unroll
            for (int j = 0; j < 16; ++j) tt[j] = (int)xc[rt][j >> 2][j & 3];
            i32x4 sg;
            #pragma unroll
            for (int w = 0; w < 4; ++w)
                sg[w] = (unsigned int)(tt[4*w] & 0xFF) | ((unsigned int)(tt[4*w+1] & 0xFF) << 8)
                      | ((unsigned int)(tt[4*w+2] & 0xFF) << 16) | ((unsigned int)(tt[4*w+3] & 0xFF) << 24);
            Asgn[rt] = sg;
            i32x4 ab;
            #pragma unroll
            for (int w = 0; w < 4; ++w) ab[w] = sg[w] & 0x01010101;
            Aabs[rt] = ab;
            unsigned int b0 = 0, b1 = 0;
            #pragma unroll
            for (int j = 0; j < 8; ++j) b0 |= ((unsigned int)tt[j] & 3u) << (2 * j);
            #pragma unroll
            for (int j = 0; j < 8; ++j) b1 |= ((unsigned int)tt[8 + j] & 3u) << (2 * j);
            int v8 = q * 64 + cc * 8 + lg * 2;
            int crow = c0 + rt * 16 + lr;
            compb[(size_t)v8 * NC + crow] = (unsigned short)b0;
            compb[(size_t)(v8 + 1) * NC + crow] = (unsigned short)b1;
        }
        // MFMA from LDS
        const char* bufp = lds[cur];
        #pragma unroll
        for (int n = 0; n < 4; ++n) {
            int boff = ((n * 16 + lr) * 4 + lg) * 16;
            i32x4 Bsh = *(const i32x4*)(bufp + boff);
            i32x4 Bsl = *(const i32x4*)(bufp + 4096 + boff);
            i32x4 Bdh = *(const i32x4*)(bufp + 8192 + boff);
            i32x4 Bdl = *(const i32x4*)(bufp + 12288 + boff);
            #pragma unroll
            for (int rt = 0; rt < 2; ++rt) {
                ahi[rt][n] = __builtin_amdgcn_mfma_i32_16x16x64_i8(Aabs[rt], Bsh, ahi[rt][n], 0, 0, 0);
                ahi[rt][n] = __builtin_amdgcn_mfma_i32_16x16x64_i8(Asgn[rt], Bdh, ahi[rt][n], 0, 0, 0);
                alo[rt][n] = __builtin_amdgcn_mfma_i32_16x16x64_i8(Aabs[rt], Bsl, alo[rt][n], 0, 0, 0);
                alo[rt][n] = __builtin_amdgcn_mfma_i32_16x16x64_i8(Asgn[rt], Bdl, alo[rt][n], 0, 0, 0);
            }
        }
        if (cc < 7) {
            #pragma unroll
            for (int rt = 0; rt < 2; ++rt)
                #pragma unroll
                for (int j4 = 0; j4 < 4; ++j4) xc[rt][j4] = xn[rt][j4];
        }
        __syncthreads();
        cur ^= 1;
    }
    float* dst = cpart + (((size_t)q * NBATCH + b) * NC + c0) * DD;
    #pragma unroll
    for (int rt = 0; rt < 2; ++rt)
        #pragma unroll
        for (int n = 0; n < 4; ++n)
            #pragma unroll
            for (int r = 0; r < 4; ++r) {
                float v = (float)(ahi[rt][n][r] * 256 + alo[rt][n][r]) * (1.0f / 4096.0f);
                dst[(size_t)(rt * 16 + lg * 4 + r) * DD + n * 16 + lr] = v;
            }
}

// ---------------------------------------------------------------------------
// K2: c = relu(sum_q cpart + cb); emit (c@v0^T +/- c@v1^T)/2 hi/lo bf16, tiled
// ---------------------------------------------------------------------------
__global__ __launch_bounds__(256) void k_projC(
    const float* __restrict__ cpart, const float* __restrict__ cb,
    const float* __restrict__ vblk,
    unsigned short* __restrict__ csh, unsigned short* __restrict__ csl,
    unsigned short* __restrict__ cdh, unsigned short* __restrict__ cdl)
{
    __shared__ float src[32][64];
    __shared__ float svb[2][64][65];
    int blk = blockIdx.x;
    int b = blk >> 8, kc = blk & 255;
    int t = threadIdx.x;
    const size_t qs = (size_t)NBATCH * NC * DD;
    const float* cs = cpart + ((size_t)b * NC + (size_t)kc * 32) * DD;
    for (int i = t; i < 2048; i += 256) {
        int k = i & 63;
        float v = cb[k];
        #pragma unroll
        for (int p = 0; p < 4; ++p) v += cs[i + p * qs];
        src[i >> 6][k] = fmaxf(v, 0.f);
    }
    for (int i = t; i < 8192; i += 256) {
        int pn = i >> 12, dout = (i >> 6) & 63, k = i & 63;
        svb[pn][k][dout] = vblk[i];
    }
    __syncthreads();
    int ks = t >> 6, dout = t & 63;
    float ap[8] = {0.f, 0.f, 0.f, 0.f, 0.f, 0.f, 0.f, 0.f};
    float an[8] = {0.f, 0.f, 0.f, 0.f, 0.f, 0.f, 0.f, 0.f};
    for (int k = 0; k < 64; ++k) {
        float w0 = svb[0][k][dout], w1 = svb[1][k][dout];
        #pragma unroll
        for (int c8 = 0; c8 < 8; ++c8) {
            float rc = src[ks * 8 + c8][k];
            ap[c8] += rc * w0;
            an[c8] += rc * w1;
        }
    }
    u16x8 vsh, vsl, vdh, vdl;
    #pragma unroll
    for (int c8 = 0; c8 < 8; ++c8) {
        float s = (ap[c8] + an[c8]) * 0.5f, dv = (ap[c8] - an[c8]) * 0.5f;
        unsigned short h = bf16_rne(s);
        vsh[c8] = h; vsl[c8] = bf16_rne(s - bf16_f32(h));
        h = bf16_rne(dv);
        vdh[c8] = h; vdl[c8] = bf16_rne(dv - bf16_f32(h));
    }
    size_t obase = (size_t)b * NC * DD + (((size_t)kc * 4 + ks) * 64 + dout) * 8;
    *(u16x8*)(csh + obase) = vsh;
    *(u16x8*)(csl + obase) = vsl;
    *(u16x8*)(cdh + obase) = vdh;
    *(u16x8*)(cdl + obase) = vdl;
}

// ---------------------------------------------------------------------------
// K3: npart[q][b][v][d] = |A|@(csh+csl) + A@(cdh+cdl) bf16, A from comp codes.
// 256-row 4-wave blocks, K64 chunks, global_load_lds double-buffer.
// grid 512 x 256. blk = rg*64 + (b*16+q)  (same-(b,q) -> same XCD).
// ---------------------------------------------------------------------------
__global__ __launch_bounds__(256, 2) void k_phaseB(
    const unsigned short* __restrict__ comp,
    const unsigned short* __restrict__ csh, const unsigned short* __restrict__ csl,
    const unsigned short* __restrict__ cdh, const unsigned short* __restrict__ cdl,
    float* __restrict__ npart)
{
    __shared__ short lds[2][16384];
    int blk = blockIdx.x;
    int combo = blk & 63;
    int rg = blk >> 6;
    int b = combo >> 4;
    int q = combo & 15;
    int t = threadIdx.x;
    int wv = t >> 6, l = t & 63, lr = l & 15, lg = l >> 4;
    int v0 = rg * 256 + wv * 64;
    const unsigned short* compb = comp + (size_t)b * 256 * NC;
    const size_t cvb = (size_t)b * NC * DD;
    int sh_ = 2 * (lr & 7);
    const unsigned short* cp[4];
    #pragma unroll
    for (int rt = 0; rt < 4; ++rt)
        cp[rt] = compb + (size_t)((v0 + rt * 16 + lr) >> 3) * NC + q * 512 + lg * 8;

    fx4 acc[4][4];
    #pragma unroll
    for (int i = 0; i < 4; ++i)
        #pragma unroll
        for (int j = 0; j < 4; ++j) acc[i][j] = (fx4){0.f, 0.f, 0.f, 0.f};

    // prologue: stage chunk 0 + comp chunk 0
    {
        size_t gb = cvb + (size_t)(q * 8) * 4096 + (size_t)t * 8;   // shorts
        short* lp = &lds[0][t * 8];
        gload_lds16(csh + gb, lp);           gload_lds16(csh + gb + 2048, lp + 2048);
        gload_lds16(csl + gb, lp + 4096);    gload_lds16(csl + gb + 2048, lp + 6144);
        gload_lds16(cdh + gb, lp + 8192);    gload_lds16(cdh + gb + 2048, lp + 10240);
        gload_lds16(cdl + gb, lp + 12288);   gload_lds16(cdl + gb + 2048, lp + 14336);
    }
    u16x8 uc[4][2], un[4][2];
    #pragma unroll
    for (int rt = 0; rt < 4; ++rt) {
        uc[rt][0] = *(const u16x8*)(cp[rt]);
        uc[rt][1] = *(const u16x8*)(cp[rt] + 32);
    }
    __syncthreads();

    int cur = 0;
    #pragma unroll 1
    for (int cc = 0; cc < 8; ++cc) {
        if (cc < 7) {
            size_t gb = cvb + (size_t)(q * 8 + cc + 1) * 4096 + (size_t)t * 8;
            short* lp = &lds[cur ^ 1][t * 8];
            gload_lds16(csh + gb, lp);           gload_lds16(csh + gb + 2048, lp + 2048);
            gload_lds16(csl + gb, lp + 4096);    gload_lds16(csl + gb + 2048, lp + 6144);
            gload_lds16(cdh + gb, lp + 8192);    gload_lds16(cdh + gb + 2048, lp + 10240);
            gload_lds16(cdl + gb, lp + 12288);   gload_lds16(cdl + gb + 2048, lp + 14336);
            #pragma unroll
            for (int rt = 0; rt < 4; ++rt) {
                un[rt][0] = *(const u16x8*)(cp[rt] + (cc + 1) * 64);
                un[rt][1] = *(const u16x8*)(cp[rt] + (cc + 1) * 64 + 32);
            }
        }
        const short* bufp = &lds[cur][0];
        #pragma unroll
        for (int st = 0; st < 2; ++st) {
            s16x8 As[4], Aa[4];
            #pragma unroll
            for (int rt = 0; rt < 4; ++rt) {
                #pragma unroll
                for (int i = 0; i < 8; ++i) {
                    unsigned int tb = ((unsigned int)uc[rt][st][i] >> sh_) & 3u;
                    unsigned short m = (tb & 1u) ? (unsigned short)0x3F80 : (unsigned short)0;
                    As[rt][i] = (short)m;
                    Aa[rt][i] = (short)(m | ((tb & 2u) << 14));
                }
            }
            #pragma unroll
            for (int n = 0; n < 4; ++n) {
                int off = ((st * 4 + lg) * 64 + n * 16 + lr) * 8;
                s16x8 Bs0 = *(const s16x8*)(bufp + off);
                s16x8 Bs1 = *(const s16x8*)(bufp + 4096 + off);
                s16x8 Bd0 = *(const s16x8*)(bufp + 8192 + off);
                s16x8 Bd1 = *(const s16x8*)(bufp + 12288 + off);
                #pragma unroll
                for (int rt = 0; rt < 4; ++rt) {
                    acc[rt][n] = __builtin_amdgcn_mfma_f32_16x16x32_bf16(As[rt], Bs0, acc[rt][n], 0, 0, 0);
                    acc[rt][n] = __builtin_amdgcn_mfma_f32_16x16x32_bf16(As[rt], Bs1, acc[rt][n], 0, 0, 0);
                    acc[rt][n] = __builtin_amdgcn_mfma_f32_16x16x32_bf16(Aa[rt], Bd0, acc[rt][n], 0, 0, 0);
                    acc[rt][n] = __builtin_amdgcn_mfma_f32_16x16x32_bf16(Aa[rt], Bd1, acc[rt][n], 0, 0, 0);
                }
            }
        }
        if (cc < 7) {
            #pragma unroll
            for (int rt = 0; rt < 4; ++rt) { uc[rt][0] = un[rt][0]; uc[rt][1] = un[rt][1]; }
        }
        __syncthreads();
        cur ^= 1;
    }
    float* dst = npart + (((size_t)q * NBATCH + b) * NV + v0) * DD;
    #pragma unroll
    for (int rt = 0; rt < 4; ++rt)
        #pragma unroll
        for (int n = 0; n < 4; ++n)
            #pragma unroll
            for (int r = 0; r < 4; ++r)
                dst[(size_t)(rt * 16 + lg * 4 + r) * DD + n * 16 + lr] = acc[rt][n][r];
}

// ---------------------------------------------------------------------------
// K4: v_emb=relu(sum_q npart+vb); av=tanh([g|v_emb]@Wg^T+bg); GRU -> out (f32)
// grid 256 x 512, 4 row-iterations per block (weights staged once).
// ---------------------------------------------------------------------------
__global__ __launch_bounds__(512) void k_gru(
    const float* __restrict__ npart, const float* __restrict__ vars,
    const float* __restrict__ gv, const float* __restrict__ vb,
    const float* __restrict__ Wg, const float* __restrict__ bg,
    const float* __restrict__ Wz, const float* __restrict__ Uz, const float* __restrict__ bz,
    const float* __restrict__ Wr, const float* __restrict__ Ur, const float* __restrict__ brr,
    const float* __restrict__ Wh, const float* __restrict__ Uh, const float* __restrict__ bh,
    float* __restrict__ out)
{
    __shared__ float sWg[72][65];
    __shared__ float sWz[64][65], sUz[64][65];
    __shared__ float sWr[64][65], sUr[64][65];
    __shared__ float sWh[64][65], sUh[64][65];
    __shared__ float scat[8][72];
    __shared__ float sprev[8][64];
    __shared__ float sav[8][64];
    __shared__ float srp[8][64];
    int t = threadIdx.x;
    for (int i = t * 4; i < 4608; i += 2048) {
        fx4 g4 = *(const fx4*)(Wg + i);
        int dout = i / 72, j = i - dout * 72;
        #pragma unroll
        for (int jj = 0; jj < 4; ++jj) sWg[j + jj][dout] = g4[jj];
    }
    for (int i = t * 4; i < 4096; i += 2048) {
        int dout = i >> 6, k = i & 63;
        fx4 a;
        a = *(const fx4*)(Wz + i);
        #pragma unroll
        for (int jj = 0; jj < 4; ++jj) sWz[k + jj][dout] = a[jj];
        a = *(const fx4*)(Uz + i);
        #pragma unroll
        for (int jj = 0; jj < 4; ++jj) sUz[k + jj][dout] = a[jj];
        a = *(const fx4*)(Wr + i);
        #pragma unroll
        for (int jj = 0; jj < 4; ++jj) sWr[k + jj][dout] = a[jj];
        a = *(const fx4*)(Ur + i);
        #pragma unroll
        for (int jj = 0; jj < 4; ++jj) sUr[k + jj][dout] = a[jj];
        a = *(const fx4*)(Wh + i);
        #pragma unroll
        for (int jj = 0; jj < 4; ++jj) sWh[k + jj][dout] = a[jj];
        a = *(const fx4*)(Uh + i);
        #pragma unroll
        for (int jj = 0; jj < 4; ++jj) sUh[k + jj][dout] = a[jj];
    }
    int rr = t >> 6, dout = t & 63;
    const size_t qs = (size_t)NBATCH * NV * DD;
    #pragma unroll 1
    for (int it = 0; it < 4; ++it) {
        size_t row = (size_t)blockIdx.x * 32 + it * 8 + rr;
        float prev = vars[row * 64 + dout];
        float ve = vb[dout];
        #pragma unroll
        for (int s = 0; s < 16; ++s) ve += npart[(size_t)s * qs + row * 64 + dout];
        ve = fmaxf(ve, 0.f);
        scat[rr][8 + dout] = ve;
        if (dout < 8) scat[rr][dout] = gv[row * 8 + dout];
        sprev[rr][dout] = prev;
        __syncthreads();
        float a = bg[dout];
        for (int j = 0; j < 72; ++j) a += scat[rr][j] * sWg[j][dout];
        float av = 1.f - 2.f / (__expf(2.f * a) + 1.f);
        sav[rr][dout] = av;
        __syncthreads();
        float zi = bz[dout], ri = brr[dout], hwa = 0.f;
        for (int k = 0; k < 64; ++k) {
            float ak = sav[rr][k], pk = sprev[rr][k];
            zi += ak * sWz[k][dout] + pk * sUz[k][dout];
            ri += ak * sWr[k][dout] + pk * sUr[k][dout];
            hwa += ak * sWh[k][dout];
        }
        float z = 1.f / (1.f + __expf(-zi));
        float rgate = 1.f / (1.f + __expf(-ri));
        srp[rr][dout] = rgate * prev;
        __syncthreads();
        float hin = bh[dout] + hwa;
        for (int k = 0; k < 64; ++k) hin += srp[rr][k] * sUh[k][dout];
        float ht = 1.f - 2.f / (__expf(2.f * hin) + 1.f);
        out[row * 64 + dout] = (1.f - z) * prev + z * ht;
        __syncthreads();
    }
}

// ---------------------------------------------------------------------------
extern "C" void kernel_launch(void* const* d_in, const int* in_sizes, int n_in,
                              void* d_out, int out_size, void* d_ws, size_t ws_size,
                              hipStream_t stream) {
    (void)in_sizes; (void)n_in; (void)out_size; (void)ws_size;
    const float* vars = (const float*)d_in[0];
    const float* gv   = (const float*)d_in[1];
    const float* cmat = (const float*)d_in[2];
    const float* cblk = (const float*)d_in[4];
    const float* vblk = (const float*)d_in[5];
    const float* vb   = (const float*)d_in[6];
    const float* cb   = (const float*)d_in[7];
    const float* Wg   = (const float*)d_in[8];
    const float* bg   = (const float*)d_in[9];
    const float* Wz   = (const float*)d_in[10];
    const float* Uz   = (const float*)d_in[11];
    const float* bz   = (const float*)d_in[12];
    const float* Wr   = (const float*)d_in[13];
    const float* Ur   = (const float*)d_in[14];
    const float* br_  = (const float*)d_in[15];
    const float* Wh   = (const float*)d_in[16];
    const float* Uh   = (const float*)d_in[17];
    const float* bh   = (const float*)d_in[18];
    float* out = (float*)d_out;

    char* w = (char*)d_ws;
    const size_t MB = 1024 * 1024;
    char* qsh = w + 0 * MB;
    char* qsl = w + 1 * MB;          // each 512 KB used
    char* qdh = w + 2 * MB;
    char* qdl = w + 3 * MB;
    unsigned short* csh = (unsigned short*)(w + 4 * MB);
    unsigned short* csl = (unsigned short*)(w + 8 * MB);
    unsigned short* cdh = (unsigned short*)(w + 12 * MB);
    unsigned short* cdl = (unsigned short*)(w + 16 * MB);
    float* cpart         = (float*)(w + 20 * MB);           // 32 MB [4][B][NC][DD]
    float* npart         = (float*)(w + 52 * MB);           // 32 MB [16][B][NV][DD]
    unsigned short* comp = (unsigned short*)(w + 84 * MB);  // 16 MB [B][256][NC]

    k_prep_pv<<<256, 256, 0, stream>>>(vars, cblk, qsh, qsl, qdh, qdl);
    k_phaseA<<<1024, 256, 0, stream>>>(cmat, qsh, qsl, qdh, qdl, cpart, comp);
    k_projC<<<1024, 256, 0, stream>>>(cpart, cb, vblk, csh, csl, cdh, cdl);
    k_phaseB<<<512, 256, 0, stream>>>(comp, csh, csl, cdh, cdl, npart);
    k_gru<<<256, 512, 0, stream>>>(npart, vars, gv, vb, Wg, bg,
                                   Wz, Uz, bz, Wr, Ur, br_, Wh, Uh, bh, out);
}